// Round 6
// baseline (766.572 us; speedup 1.0000x reference)
//
#include <hip/hip_runtime.h>

typedef unsigned short ushort_t;

#define LN_EPS 1e-5f

// ---- bf16 <-> f32 helpers ----
__device__ __forceinline__ float b2f(ushort_t u) {
    return __uint_as_float(((unsigned)u) << 16);
}
__device__ __forceinline__ ushort_t f2b(float f) {
    unsigned b = __float_as_uint(f);
    b += 0x7FFFu + ((b >> 16) & 1u);  // round-to-nearest-even
    return (ushort_t)(b >> 16);
}
// dtype-flexible load: isF ? fp32 : bf16
__device__ __forceinline__ float ldf(const void* p, size_t i, int isF) {
    return isF ? ((const float*)p)[i] : b2f(((const ushort_t*)p)[i]);
}

// harness-compat symbol (unused)
__global__ void GraphSAGE_36026185678961_kernel() {}

// ---------------- dtype detector ----------------
// flags[0]=1 if float inputs are fp32 (else bf16); flags[1]=1 if ints are int64 (else int32)
__global__ void k_detect(const void* w0, const void* ei, int* __restrict__ flags) {
    int t = threadIdx.x;  // 64 threads
    const ushort_t* u = (const ushort_t*)w0;
    int pass = 0;
    #pragma unroll
    for (int k = 0; k < 4; ++k) {
        ushort_t v = u[t * 4 + k];
        int ex = (v >> 7) & 0xFF;
        if (ex == 0 || (ex >= 0x60 && ex <= 0x7E)) pass++;  // plausible bf16 glorot value
    }
    const unsigned* w = (const unsigned*)ei;
    int nz = (w[2 * t + 1] != 0u) ? 1 : 0;  // odd words: 0 for int64 (<50000), random for int32
    #pragma unroll
    for (int off = 32; off; off >>= 1) {
        pass += __shfl_down(pass, off, 64);
        nz += __shfl_down(nz, off, 64);
    }
    if (t == 0) {
        flags[0] = (pass < 205) ? 1 : 0;  // <80% of 256 samples plausible -> fp32
        flags[1] = (nz == 0) ? 1 : 0;     // all odd words zero -> int64
    }
}

// ---------------- zero-init: deg, Z, col, zflags ----------------
__global__ void k_zero(int* __restrict__ deg, float* __restrict__ Z,
                       int* __restrict__ col, int* __restrict__ zflags, int N, int E) {
    int i = blockIdx.x * blockDim.x + threadIdx.x;
    if (i < N) deg[i] = 0;
    if (i < 64 * 128) Z[i] = 0.f;
    if (i < E) col[i] = 0;
    if (i < 4) zflags[i] = 0;
}

// ---------------- edge conversion to int32 ----------------
__global__ void k_edges(const void* ei, int E, const int* __restrict__ flags,
                        int* __restrict__ s32, int* __restrict__ d32) {
    int e = blockIdx.x * blockDim.x + threadIdx.x;
    if (e >= E) return;
    if (flags[1]) {
        const long long* p = (const long long*)ei;
        s32[e] = (int)p[e];
        d32[e] = (int)p[E + e];
    } else {
        const int* p = (const int*)ei;
        s32[e] = p[e];
        d32[e] = p[E + e];
    }
}

// ---------------- CSR build ----------------
__global__ void k_hist(const int* __restrict__ dst, int E, int N, int* __restrict__ deg) {
    int e = blockIdx.x * blockDim.x + threadIdx.x;
    if (e < E) {
        int d = dst[e];
        if ((unsigned)d < (unsigned)N) atomicAdd(&deg[d], 1);
    }
}

// single-block exclusive scan, 256 threads (4 waves)
__global__ void k_scan(const int* __restrict__ deg, int N,
                       int* __restrict__ rowptr, int* __restrict__ cursor) {
    __shared__ int wsum[4];
    __shared__ int wpre[4];
    int tid = threadIdx.x;
    int lane = tid & 63;
    int w = tid >> 6;
    int run = 0;
    for (int base = 0; base < N; base += 256) {
        int i = base + tid;
        int v = (i < N) ? deg[i] : 0;
        int x = v;
        #pragma unroll
        for (int off = 1; off < 64; off <<= 1) {
            int t = __shfl_up(x, off, 64);
            if (lane >= off) x += t;
        }
        if (lane == 63) wsum[w] = x;
        __syncthreads();
        if (tid == 0) {
            int a = wsum[0]; wpre[0] = a;
            a += wsum[1]; wpre[1] = a;
            a += wsum[2]; wpre[2] = a;
            a += wsum[3]; wpre[3] = a;
        }
        __syncthreads();
        int woff = (w == 0) ? 0 : wpre[w - 1];
        if (i < N) {
            int ex = run + woff + x - v;
            rowptr[i] = ex;
            cursor[i] = ex;
        }
        int tot = wpre[3];
        __syncthreads();
        run += tot;
    }
    if (tid == 0) rowptr[N] = run;
}

__global__ void k_fill(const int* __restrict__ src, const int* __restrict__ dst, int E, int N,
                       int* __restrict__ cursor, int* __restrict__ col) {
    int e = blockIdx.x * blockDim.x + threadIdx.x;
    if (e < E) {
        int d = dst[e];
        if ((unsigned)d < (unsigned)N) {
            int p = atomicAdd(&cursor[d], 1);
            if ((unsigned)p < (unsigned)E) {
                int s = src[e];
                col[p] = ((unsigned)s < (unsigned)N) ? s : 0;
            }
        }
    }
}

__global__ void k_bounds(const void* batch, int N, int G, const int* __restrict__ flags,
                         int* __restrict__ bounds) {
    int g = threadIdx.x;
    if (g > G) return;
    int isL = flags[1];
    int lo = 0, hi = N;
    while (lo < hi) {
        int mid = (lo + hi) >> 1;
        int bv = isL ? (int)((const long long*)batch)[mid] : ((const int*)batch)[mid];
        if (bv < g) lo = mid + 1; else hi = mid;
    }
    bounds[g] = lo;
}

// ---------------- mean aggregation: AGG[i] = mean_{j in N(i)} X[j]  (128-wide) ----------------
// X dtype governed by xflags[0] (fp32 or bf16); AGG written as internal bf16.
__global__ void k_agg(const void* X, const int* __restrict__ rowptr,
                      const int* __restrict__ col, const int* __restrict__ xflags,
                      ushort_t* __restrict__ AGG, int N) {
    int isF = xflags[0];
    int i = blockIdx.x;
    int f = threadIdx.x;
    int s = rowptr[i], e = rowptr[i + 1];
    float acc = 0.f;
    for (int p = s; p < e; ++p) {
        int j = col[p];
        j = ((unsigned)j < (unsigned)N) ? j : 0;
        acc += ldf(X, (size_t)j * 128 + f, isF);
    }
    int d = e - s;
    AGG[(size_t)i * 128 + f] = f2b(acc / (float)(d > 0 ? d : 1));
}

// ---------------- weight prep: Wt[k][f] fp32 ----------------
template <int FO>
__global__ void k_wprep(const void* Wl, const void* Wr, const int* __restrict__ flags,
                        float* __restrict__ Wt) {
    int t = blockIdx.x * blockDim.x + threadIdx.x;
    if (t >= 256 * FO) return;
    int isF = flags[0];
    int f = t % FO, k = t / FO;
    Wt[t] = (k < 128) ? ldf(Wl, f * 128 + k, isF) : ldf(Wr, f * 128 + (k - 128), isF);
}

// ---------------- fused GEMM + bias + LayerNorm + ReLU (pure fp32 VALU) ----------------
// H = relu(LN([AGG|X] @ Wt + bl) * gam + bet). AGG internal bf16; X dtype per xflags.
// 256 threads; 32 feature-lane groups (FPT feats each), 8 row-groups x 4 rows = 32 rows/block.
template <int FO, int FPT>
__global__ __launch_bounds__(256) void k_gemm_ln(
    const ushort_t* __restrict__ AGG, const void* X, const float* __restrict__ Wt,
    const void* bl, const void* gam, const void* bet,
    const int* __restrict__ flags, const int* __restrict__ xflags,
    ushort_t* __restrict__ H, int M) {
    constexpr int ROWS = 32;
    __shared__ float Xs[ROWS][256];

    int tid = threadIdx.x;
    int row0 = blockIdx.x * ROWS;
    int isF = flags[0];    // param dtype
    int isFx = xflags[0];  // X dtype

    for (int r = 0; r < ROWS; ++r) {
        int row = row0 + r;
        float v = 0.f;
        if (row < M)
            v = (tid < 128) ? b2f(AGG[(size_t)row * 128 + tid])
                            : ldf(X, (size_t)row * 128 + (tid - 128), isFx);
        Xs[r][tid] = v;
    }
    __syncthreads();

    int fi = tid & 31;
    int ri = tid >> 5;
    int f0 = fi * FPT;
    int r0 = ri * 4;

    float acc[4][FPT];
    #pragma unroll
    for (int j = 0; j < 4; ++j)
        #pragma unroll
        for (int p = 0; p < FPT; ++p) acc[j][p] = 0.f;

    #pragma unroll 2
    for (int kb = 0; kb < 256; kb += 4) {
        float4 xr[4];
        #pragma unroll
        for (int j = 0; j < 4; ++j) xr[j] = *(const float4*)&Xs[r0 + j][kb];
        #pragma unroll
        for (int kk = 0; kk < 4; ++kk) {
            float wv[FPT];
            #pragma unroll
            for (int p = 0; p < FPT; ++p) wv[p] = Wt[(kb + kk) * FO + f0 + p];
            #pragma unroll
            for (int j = 0; j < 4; ++j) {
                float xk = ((const float*)&xr[j])[kk];
                #pragma unroll
                for (int p = 0; p < FPT; ++p) acc[j][p] += xk * wv[p];
            }
        }
    }

    float bv[FPT];
    #pragma unroll
    for (int p = 0; p < FPT; ++p) bv[p] = ldf(bl, f0 + p, isF);
    #pragma unroll
    for (int j = 0; j < 4; ++j)
        #pragma unroll
        for (int p = 0; p < FPT; ++p) acc[j][p] += bv[p];

    float mu[4], rs[4];
    #pragma unroll
    for (int j = 0; j < 4; ++j) {
        float s1 = 0.f, s2 = 0.f;
        #pragma unroll
        for (int p = 0; p < FPT; ++p) {
            float v = acc[j][p];
            s1 += v;
            s2 += v * v;
        }
        #pragma unroll
        for (int off = 1; off < 32; off <<= 1) {
            s1 += __shfl_xor(s1, off, 64);
            s2 += __shfl_xor(s2, off, 64);
        }
        float m = s1 / (float)FO;
        float var = s2 / (float)FO - m * m;
        var = var > 0.f ? var : 0.f;
        mu[j] = m;
        rs[j] = rsqrtf(var + LN_EPS);
    }

    float gv[FPT], ev[FPT];
    #pragma unroll
    for (int p = 0; p < FPT; ++p) {
        gv[p] = ldf(gam, f0 + p, isF);
        ev[p] = ldf(bet, f0 + p, isF);
    }
    #pragma unroll
    for (int j = 0; j < 4; ++j) {
        int row = row0 + r0 + j;
        if (row >= M) break;
        #pragma unroll
        for (int p = 0; p < FPT; ++p) {
            float y = (acc[j][p] - mu[j]) * rs[j] * gv[p] + ev[p];
            y = y > 0.f ? y : 0.f;
            H[(size_t)row * FO + f0 + p] = f2b(y);
        }
    }
}

// ---------------- pooling: Z[64][128]: cols 0..63 sum, 64..127 max ----------------
__global__ void k_pool(const ushort_t* __restrict__ H,  // [N,64], post-ReLU (>=0)
                       const int* __restrict__ bounds, float* __restrict__ Z, int N) {
    int g = blockIdx.x >> 3;
    int chunk = blockIdx.x & 7;
    int f = threadIdx.x & 63;
    int sub = threadIdx.x >> 6;
    int strm = chunk * 4 + sub;
    int s = bounds[g], e = bounds[g + 1];
    s = s < 0 ? 0 : (s > N ? N : s);
    e = e < s ? s : (e > N ? N : e);
    float sum = 0.f, mx = 0.f;
    for (int i = s + strm; i < e; i += 32) {
        float v = b2f(H[(size_t)i * 64 + f]);
        sum += v;
        mx = mx > v ? mx : v;
    }
    atomicAdd(&Z[g * 128 + f], sum);
    atomicMax((int*)&Z[g * 128 + 64 + f], __float_as_int(mx));
}

// ---------------- final MLP; output dtype follows flags[0] ----------------
__global__ void k_mlp(const float* __restrict__ Z, const int* __restrict__ bounds,
                      const void* cW1, const void* cb1, const void* cW2, const void* cb2,
                      const int* __restrict__ flags, void* __restrict__ out) {
    int g = blockIdx.x;
    int f = threadIdx.x;  // 0..127
    int isF = flags[0];
    __shared__ float z[128];
    __shared__ float hid[128];
    __shared__ float r0[2], r1[2];
    int cnt = bounds[g + 1] - bounds[g];
    float c = (float)(cnt > 0 ? cnt : 1);
    float zv = Z[g * 128 + f];
    if (f < 64) zv /= c;
    z[f] = zv;
    __syncthreads();
    float acc = ldf(cb1, f, isF);
    #pragma unroll 8
    for (int k = 0; k < 128; ++k) acc += z[k] * ldf(cW1, f * 128 + k, isF);
    acc = acc > 0.f ? acc : 0.f;
    hid[f] = acc;
    __syncthreads();
    float p0 = hid[f] * ldf(cW2, f, isF);
    float p1 = hid[f] * ldf(cW2, 128 + f, isF);
    #pragma unroll
    for (int off = 32; off > 0; off >>= 1) {
        p0 += __shfl_xor(p0, off, 64);
        p1 += __shfl_xor(p1, off, 64);
    }
    int w = f >> 6;
    if ((f & 63) == 0) { r0[w] = p0; r1[w] = p1; }
    __syncthreads();
    if (f == 0) {
        float v0 = r0[0] + r0[1] + ldf(cb2, 0, isF);
        float v1 = r1[0] + r1[1] + ldf(cb2, 1, isF);
        if (isF) {
            ((float*)out)[g * 2 + 0] = v0;
            ((float*)out)[g * 2 + 1] = v1;
        } else {
            ((ushort_t*)out)[g * 2 + 0] = f2b(v0);
            ((ushort_t*)out)[g * 2 + 1] = f2b(v1);
        }
    }
}

// ---------------- launch ----------------
extern "C" void kernel_launch(void* const* d_in, const int* in_sizes, int n_in,
                              void* d_out, int out_size, void* d_ws, size_t ws_size,
                              hipStream_t stream) {
    const void* x = d_in[0];
    const void* ei = d_in[1];
    const void* batch = d_in[2];
    const void* Wl0 = d_in[3];
    const void* bl0 = d_in[4];
    const void* Wr0 = d_in[5];
    const void* g0 = d_in[6];
    const void* be0 = d_in[7];
    const void* Wl1 = d_in[8];
    const void* bl1 = d_in[9];
    const void* Wr1 = d_in[10];
    const void* g1 = d_in[11];
    const void* be1 = d_in[12];
    const void* Wl2 = d_in[13];
    const void* bl2 = d_in[14];
    const void* Wr2 = d_in[15];
    const void* g2 = d_in[16];
    const void* be2 = d_in[17];
    const void* cW1 = d_in[18];
    const void* cb1 = d_in[19];
    const void* cW2 = d_in[20];
    const void* cb2 = d_in[21];

    const int N = in_sizes[0] / 128;  // 50000
    const int E = in_sizes[1] / 2;    // 600000
    const int G = 64;

    // workspace carve-up (256B aligned slots); ~47 MB total
    char* w = (char*)d_ws;
    size_t o = 0;
    auto take = [&](size_t bytes) -> void* {
        void* p = w + o;
        o = (o + bytes + 255) & ~(size_t)255;
        return p;
    };
    int* flags  = (int*)take(4 * 4);
    int* zflags = (int*)take(4 * 4);
    int* rowptr = (int*)take((size_t)(N + 1) * 4);
    int* cursor = (int*)take((size_t)N * 4);
    int* deg    = (int*)take((size_t)N * 4);
    int* col    = (int*)take((size_t)E * 4);
    int* src32  = (int*)take((size_t)E * 4);
    int* dst32  = (int*)take((size_t)E * 4);
    int* bounds = (int*)take((size_t)(G + 1) * 4);
    float* Z    = (float*)take((size_t)G * 128 * 4);
    float* Wt0  = (float*)take((size_t)256 * 128 * 4);
    float* Wt1  = (float*)take((size_t)256 * 128 * 4);
    float* Wt2  = (float*)take((size_t)256 * 64 * 4);
    ushort_t* AGG = (ushort_t*)take((size_t)N * 128 * 2);
    ushort_t* H1  = (ushort_t*)take((size_t)N * 128 * 2);
    ushort_t* H2  = (ushort_t*)take((size_t)N * 128 * 2);
    ushort_t* H3  = H1;  // [N,64], reuses H1
    if (o > ws_size) return;  // ws too small -> zeros signature (diagnostic)

    int eb = (E + 255) / 256;
    k_detect<<<1, 64, 0, stream>>>(Wl0, ei, flags);
    k_zero<<<eb, 256, 0, stream>>>(deg, Z, col, zflags, N, E);
    k_edges<<<eb, 256, 0, stream>>>(ei, E, flags, src32, dst32);
    k_hist<<<eb, 256, 0, stream>>>(dst32, E, N, deg);
    k_scan<<<1, 256, 0, stream>>>(deg, N, rowptr, cursor);
    k_fill<<<eb, 256, 0, stream>>>(src32, dst32, E, N, cursor, col);
    k_bounds<<<1, 128, 0, stream>>>(batch, N, G, flags, bounds);
    k_wprep<128><<<128, 256, 0, stream>>>(Wl0, Wr0, flags, Wt0);
    k_wprep<128><<<128, 256, 0, stream>>>(Wl1, Wr1, flags, Wt1);
    k_wprep<64><<<64, 256, 0, stream>>>(Wl2, Wr2, flags, Wt2);

    int gb = (N + 31) / 32;

    // layer 0: x -> H1   (X dtype = flags)
    k_agg<<<N, 128, 0, stream>>>(x, rowptr, col, flags, AGG, N);
    k_gemm_ln<128, 4><<<gb, 256, 0, stream>>>(AGG, x, Wt0, bl0, g0, be0, flags, flags, H1, N);
    // layer 1: H1 -> H2  (X dtype = internal bf16 -> zflags)
    k_agg<<<N, 128, 0, stream>>>(H1, rowptr, col, zflags, AGG, N);
    k_gemm_ln<128, 4><<<gb, 256, 0, stream>>>(AGG, H1, Wt1, bl1, g1, be1, flags, zflags, H2, N);
    // layer 2: H2 -> H3 [N,64]
    k_agg<<<N, 128, 0, stream>>>(H2, rowptr, col, zflags, AGG, N);
    k_gemm_ln<64, 2><<<gb, 256, 0, stream>>>(AGG, H2, Wt2, bl2, g2, be2, flags, zflags, H3, N);

    k_pool<<<G * 8, 256, 0, stream>>>(H3, bounds, Z, N);
    k_mlp<<<G, 128, 0, stream>>>(Z, bounds, cW1, cb1, cW2, cb2, flags, d_out);
}

// Round 7
// 531.562 us; speedup vs baseline: 1.4421x; 1.4421x over previous
//
#include <hip/hip_runtime.h>

typedef unsigned short ushort_t;

#define LN_EPS 1e-5f

// ---- bf16 <-> f32 helpers ----
__device__ __forceinline__ float b2f(ushort_t u) {
    return __uint_as_float(((unsigned)u) << 16);
}
__device__ __forceinline__ ushort_t f2b(float f) {
    unsigned b = __float_as_uint(f);
    b += 0x7FFFu + ((b >> 16) & 1u);  // round-to-nearest-even
    return (ushort_t)(b >> 16);
}
// dtype-flexible load: isF ? fp32 : bf16
__device__ __forceinline__ float ldf(const void* p, size_t i, int isF) {
    return isF ? ((const float*)p)[i] : b2f(((const ushort_t*)p)[i]);
}

// harness-compat symbol (unused)
__global__ void GraphSAGE_36026185678961_kernel() {}

// ---------------- dtype detector ----------------
// flags[0]=1 if float inputs are fp32 (else bf16); flags[1]=1 if ints are int64 (else int32)
__global__ void k_detect(const void* w0, const void* ei, int* __restrict__ flags) {
    int t = threadIdx.x;  // 64 threads
    const ushort_t* u = (const ushort_t*)w0;
    int pass = 0;
    #pragma unroll
    for (int k = 0; k < 4; ++k) {
        ushort_t v = u[t * 4 + k];
        int ex = (v >> 7) & 0xFF;
        if (ex == 0 || (ex >= 0x60 && ex <= 0x7E)) pass++;  // plausible bf16 glorot value
    }
    const unsigned* w = (const unsigned*)ei;
    int nz = (w[2 * t + 1] != 0u) ? 1 : 0;  // odd words: 0 for int64 (<50000), random for int32
    #pragma unroll
    for (int off = 32; off; off >>= 1) {
        pass += __shfl_down(pass, off, 64);
        nz += __shfl_down(nz, off, 64);
    }
    if (t == 0) {
        flags[0] = (pass < 205) ? 1 : 0;  // <80% of 256 samples plausible -> fp32
        flags[1] = (nz == 0) ? 1 : 0;     // all odd words zero -> int64
    }
}

// ---------------- zero-init: deg, Z ----------------
__global__ void k_zero(int* __restrict__ deg, float* __restrict__ Z, int N) {
    int i = blockIdx.x * blockDim.x + threadIdx.x;
    if (i < N) deg[i] = 0;
    if (i < 64 * 128) Z[i] = 0.f;
}

// ---------------- x -> bf16 conversion (layer-0 input) ----------------
__global__ void k_xconv(const void* X, const int* __restrict__ flags,
                        ushort_t* __restrict__ XB, int total4) {
    int idx = blockIdx.x * blockDim.x + threadIdx.x;  // one float4/ushort4 group
    if (idx >= total4) return;
    if (flags[0]) {
        float4 v = ((const float4*)X)[idx];
        ushort4 o;
        o.x = f2b(v.x); o.y = f2b(v.y); o.z = f2b(v.z); o.w = f2b(v.w);
        ((ushort4*)XB)[idx] = o;
    } else {
        ((ushort4*)XB)[idx] = ((const ushort4*)X)[idx];
    }
}

// ---------------- edge conversion to int32 ----------------
__global__ void k_edges(const void* ei, int E, const int* __restrict__ flags,
                        int* __restrict__ s32, int* __restrict__ d32) {
    int e = blockIdx.x * blockDim.x + threadIdx.x;
    if (e >= E) return;
    if (flags[1]) {
        const long long* p = (const long long*)ei;
        s32[e] = (int)p[e];
        d32[e] = (int)p[E + e];
    } else {
        const int* p = (const int*)ei;
        s32[e] = p[e];
        d32[e] = p[E + e];
    }
}

// ---------------- CSR build ----------------
__global__ void k_hist(const int* __restrict__ dst, int E, int N, int* __restrict__ deg) {
    int e = blockIdx.x * blockDim.x + threadIdx.x;
    if (e < E) {
        int d = dst[e];
        if ((unsigned)d < (unsigned)N) atomicAdd(&deg[d], 1);
    }
}

// hierarchical scan, phase 1: per-block (256-elem) exclusive scan + block totals
__global__ void k_scan1(const int* __restrict__ deg, int N,
                        int* __restrict__ rowptr, int* __restrict__ bsum) {
    __shared__ int wsum[4];
    __shared__ int wpre[4];
    int tid = threadIdx.x;
    int lane = tid & 63;
    int w = tid >> 6;
    int i = blockIdx.x * 256 + tid;
    int v = (i < N) ? deg[i] : 0;
    int x = v;
    #pragma unroll
    for (int off = 1; off < 64; off <<= 1) {
        int t = __shfl_up(x, off, 64);
        if (lane >= off) x += t;
    }
    if (lane == 63) wsum[w] = x;
    __syncthreads();
    if (tid == 0) {
        int a = wsum[0]; wpre[0] = a;
        a += wsum[1]; wpre[1] = a;
        a += wsum[2]; wpre[2] = a;
        a += wsum[3]; wpre[3] = a;
    }
    __syncthreads();
    int woff = (w == 0) ? 0 : wpre[w - 1];
    if (i < N) rowptr[i] = woff + x - v;  // block-local exclusive
    if (tid == 0) bsum[blockIdx.x] = wpre[3];
}

// phase 2: single-block exclusive scan of block sums (nb <= a few thousand)
__global__ void k_scan2(const int* __restrict__ bsum, int nb,
                        int* __restrict__ boff, int* __restrict__ rowptrN) {
    __shared__ int wsum[4];
    __shared__ int wpre[4];
    int tid = threadIdx.x;
    int lane = tid & 63;
    int w = tid >> 6;
    int run = 0;
    for (int base = 0; base < nb; base += 256) {
        int i = base + tid;
        int v = (i < nb) ? bsum[i] : 0;
        int x = v;
        #pragma unroll
        for (int off = 1; off < 64; off <<= 1) {
            int t = __shfl_up(x, off, 64);
            if (lane >= off) x += t;
        }
        if (lane == 63) wsum[w] = x;
        __syncthreads();
        if (tid == 0) {
            int a = wsum[0]; wpre[0] = a;
            a += wsum[1]; wpre[1] = a;
            a += wsum[2]; wpre[2] = a;
            a += wsum[3]; wpre[3] = a;
        }
        __syncthreads();
        int woff = (w == 0) ? 0 : wpre[w - 1];
        if (i < nb) boff[i] = run + woff + x - v;
        int tot = wpre[3];
        __syncthreads();
        run += tot;
    }
    if (tid == 0) *rowptrN = run;  // rowptr[N] = E_total
}

// phase 3: add block offsets; produce cursor copy
__global__ void k_scan3(int* __restrict__ rowptr, const int* __restrict__ boff,
                        int* __restrict__ cursor, int N) {
    int i = blockIdx.x * 256 + threadIdx.x;
    if (i < N) {
        int r = rowptr[i] + boff[i >> 8];
        rowptr[i] = r;
        cursor[i] = r;
    }
}

__global__ void k_fill(const int* __restrict__ src, const int* __restrict__ dst, int E, int N,
                       int* __restrict__ cursor, int* __restrict__ col) {
    int e = blockIdx.x * blockDim.x + threadIdx.x;
    if (e < E) {
        int d = dst[e];
        if ((unsigned)d < (unsigned)N) {
            int p = atomicAdd(&cursor[d], 1);
            if ((unsigned)p < (unsigned)E) {
                int s = src[e];
                col[p] = ((unsigned)s < (unsigned)N) ? s : 0;
            }
        }
    }
}

__global__ void k_bounds(const void* batch, int N, int G, const int* __restrict__ flags,
                         int* __restrict__ bounds) {
    int g = threadIdx.x;
    if (g > G) return;
    int isL = flags[1];
    int lo = 0, hi = N;
    while (lo < hi) {
        int mid = (lo + hi) >> 1;
        int bv = isL ? (int)((const long long*)batch)[mid] : ((const int*)batch)[mid];
        if (bv < g) lo = mid + 1; else hi = mid;
    }
    bounds[g] = lo;
}

// ---------------- mean aggregation: AGG[i] = mean_{j in N(i)} X[j]  (bf16, 128-wide) ----------------
// one wave per node; lane handles feats {2l, 2l+1} via ushort2 (256B/row per wave-load);
// neighbors unrolled x4 with independent accumulators.
__global__ __launch_bounds__(256) void k_agg(
    const ushort_t* __restrict__ X, const int* __restrict__ rowptr,
    const int* __restrict__ col, ushort_t* __restrict__ AGG, int N) {
    int i = blockIdx.x * 4 + (threadIdx.x >> 6);
    if (i >= N) return;
    int l = threadIdx.x & 63;
    const ushort2* X2 = (const ushort2*)X;
    int s = rowptr[i], e = rowptr[i + 1];
    float a0 = 0.f, b0 = 0.f, a1 = 0.f, b1 = 0.f;
    int p = s;
    for (; p + 4 <= e; p += 4) {
        int j0 = col[p], j1 = col[p + 1], j2 = col[p + 2], j3 = col[p + 3];
        ushort2 u0 = X2[(size_t)j0 * 64 + l];
        ushort2 u1 = X2[(size_t)j1 * 64 + l];
        ushort2 u2 = X2[(size_t)j2 * 64 + l];
        ushort2 u3 = X2[(size_t)j3 * 64 + l];
        a0 += b2f(u0.x); b0 += b2f(u0.y);
        a1 += b2f(u1.x); b1 += b2f(u1.y);
        a0 += b2f(u2.x); b0 += b2f(u2.y);
        a1 += b2f(u3.x); b1 += b2f(u3.y);
    }
    for (; p < e; ++p) {
        int j = col[p];
        ushort2 u = X2[(size_t)j * 64 + l];
        a0 += b2f(u.x); b0 += b2f(u.y);
    }
    int d = e - s;
    float inv = 1.f / (float)(d > 0 ? d : 1);
    ushort2 o;
    o.x = f2b((a0 + a1) * inv);
    o.y = f2b((b0 + b1) * inv);
    ((ushort2*)AGG)[(size_t)i * 64 + l] = o;
}

// ---------------- weight prep: Wt[k][f] fp32 ----------------
template <int FO>
__global__ void k_wprep(const void* Wl, const void* Wr, const int* __restrict__ flags,
                        float* __restrict__ Wt) {
    int t = blockIdx.x * blockDim.x + threadIdx.x;
    if (t >= 256 * FO) return;
    int isF = flags[0];
    int f = t % FO, k = t / FO;
    Wt[t] = (k < 128) ? ldf(Wl, f * 128 + k, isF) : ldf(Wr, f * 128 + (k - 128), isF);
}

// ---------------- fused GEMM + bias + LayerNorm + ReLU (pure fp32 VALU) ----------------
// H = relu(LN([AGG|X] @ Wt + bl) * gam + bet). AGG and X both bf16.
// 256 threads; 32 feature-lane groups (FPT feats each), 8 row-groups x 4 rows = 32 rows/block.
template <int FO, int FPT>
__global__ __launch_bounds__(256) void k_gemm_ln(
    const ushort_t* __restrict__ AGG, const ushort_t* __restrict__ X,
    const float* __restrict__ Wt,
    const void* bl, const void* gam, const void* bet,
    const int* __restrict__ flags,
    ushort_t* __restrict__ H, int M) {
    constexpr int ROWS = 32;
    __shared__ float Xs[ROWS][256];

    int tid = threadIdx.x;
    int row0 = blockIdx.x * ROWS;
    int isF = flags[0];  // param dtype

    for (int r = 0; r < ROWS; ++r) {
        int row = row0 + r;
        float v = 0.f;
        if (row < M)
            v = (tid < 128) ? b2f(AGG[(size_t)row * 128 + tid])
                            : b2f(X[(size_t)row * 128 + (tid - 128)]);
        Xs[r][tid] = v;
    }
    __syncthreads();

    int fi = tid & 31;
    int ri = tid >> 5;
    int f0 = fi * FPT;
    int r0 = ri * 4;

    float acc[4][FPT];
    #pragma unroll
    for (int j = 0; j < 4; ++j)
        #pragma unroll
        for (int p = 0; p < FPT; ++p) acc[j][p] = 0.f;

    #pragma unroll 2
    for (int kb = 0; kb < 256; kb += 4) {
        float4 xr[4];
        #pragma unroll
        for (int j = 0; j < 4; ++j) xr[j] = *(const float4*)&Xs[r0 + j][kb];
        #pragma unroll
        for (int kk = 0; kk < 4; ++kk) {
            float wv[FPT];
            #pragma unroll
            for (int p = 0; p < FPT; ++p) wv[p] = Wt[(kb + kk) * FO + f0 + p];
            #pragma unroll
            for (int j = 0; j < 4; ++j) {
                float xk = ((const float*)&xr[j])[kk];
                #pragma unroll
                for (int p = 0; p < FPT; ++p) acc[j][p] += xk * wv[p];
            }
        }
    }

    float bv[FPT];
    #pragma unroll
    for (int p = 0; p < FPT; ++p) bv[p] = ldf(bl, f0 + p, isF);
    #pragma unroll
    for (int j = 0; j < 4; ++j)
        #pragma unroll
        for (int p = 0; p < FPT; ++p) acc[j][p] += bv[p];

    float mu[4], rs[4];
    #pragma unroll
    for (int j = 0; j < 4; ++j) {
        float s1 = 0.f, s2 = 0.f;
        #pragma unroll
        for (int p = 0; p < FPT; ++p) {
            float v = acc[j][p];
            s1 += v;
            s2 += v * v;
        }
        #pragma unroll
        for (int off = 1; off < 32; off <<= 1) {
            s1 += __shfl_xor(s1, off, 64);
            s2 += __shfl_xor(s2, off, 64);
        }
        float m = s1 / (float)FO;
        float var = s2 / (float)FO - m * m;
        var = var > 0.f ? var : 0.f;
        mu[j] = m;
        rs[j] = rsqrtf(var + LN_EPS);
    }

    float gv[FPT], ev[FPT];
    #pragma unroll
    for (int p = 0; p < FPT; ++p) {
        gv[p] = ldf(gam, f0 + p, isF);
        ev[p] = ldf(bet, f0 + p, isF);
    }
    #pragma unroll
    for (int j = 0; j < 4; ++j) {
        int row = row0 + r0 + j;
        if (row >= M) break;
        #pragma unroll
        for (int p = 0; p < FPT; ++p) {
            float y = (acc[j][p] - mu[j]) * rs[j] * gv[p] + ev[p];
            y = y > 0.f ? y : 0.f;
            H[(size_t)row * FO + f0 + p] = f2b(y);
        }
    }
}

// ---------------- pooling: Z[64][128]: cols 0..63 sum, 64..127 max ----------------
__global__ void k_pool(const ushort_t* __restrict__ H,  // [N,64], post-ReLU (>=0)
                       const int* __restrict__ bounds, float* __restrict__ Z, int N) {
    int g = blockIdx.x >> 3;
    int chunk = blockIdx.x & 7;
    int f = threadIdx.x & 63;
    int sub = threadIdx.x >> 6;
    int strm = chunk * 4 + sub;
    int s = bounds[g], e = bounds[g + 1];
    s = s < 0 ? 0 : (s > N ? N : s);
    e = e < s ? s : (e > N ? N : e);
    float sum = 0.f, mx = 0.f;
    for (int i = s + strm; i < e; i += 32) {
        float v = b2f(H[(size_t)i * 64 + f]);
        sum += v;
        mx = mx > v ? mx : v;
    }
    atomicAdd(&Z[g * 128 + f], sum);
    atomicMax((int*)&Z[g * 128 + 64 + f], __float_as_int(mx));
}

// ---------------- final MLP; output dtype follows flags[0] ----------------
__global__ void k_mlp(const float* __restrict__ Z, const int* __restrict__ bounds,
                      const void* cW1, const void* cb1, const void* cW2, const void* cb2,
                      const int* __restrict__ flags, void* __restrict__ out) {
    int g = blockIdx.x;
    int f = threadIdx.x;  // 0..127
    int isF = flags[0];
    __shared__ float z[128];
    __shared__ float hid[128];
    __shared__ float r0[2], r1[2];
    int cnt = bounds[g + 1] - bounds[g];
    float c = (float)(cnt > 0 ? cnt : 1);
    float zv = Z[g * 128 + f];
    if (f < 64) zv /= c;
    z[f] = zv;
    __syncthreads();
    float acc = ldf(cb1, f, isF);
    #pragma unroll 8
    for (int k = 0; k < 128; ++k) acc += z[k] * ldf(cW1, f * 128 + k, isF);
    acc = acc > 0.f ? acc : 0.f;
    hid[f] = acc;
    __syncthreads();
    float p0 = hid[f] * ldf(cW2, f, isF);
    float p1 = hid[f] * ldf(cW2, 128 + f, isF);
    #pragma unroll
    for (int off = 32; off > 0; off >>= 1) {
        p0 += __shfl_xor(p0, off, 64);
        p1 += __shfl_xor(p1, off, 64);
    }
    int w = f >> 6;
    if ((f & 63) == 0) { r0[w] = p0; r1[w] = p1; }
    __syncthreads();
    if (f == 0) {
        float v0 = r0[0] + r0[1] + ldf(cb2, 0, isF);
        float v1 = r1[0] + r1[1] + ldf(cb2, 1, isF);
        if (isF) {
            ((float*)out)[g * 2 + 0] = v0;
            ((float*)out)[g * 2 + 1] = v1;
        } else {
            ((ushort_t*)out)[g * 2 + 0] = f2b(v0);
            ((ushort_t*)out)[g * 2 + 1] = f2b(v1);
        }
    }
}

// ---------------- launch ----------------
extern "C" void kernel_launch(void* const* d_in, const int* in_sizes, int n_in,
                              void* d_out, int out_size, void* d_ws, size_t ws_size,
                              hipStream_t stream) {
    const void* x = d_in[0];
    const void* ei = d_in[1];
    const void* batch = d_in[2];
    const void* Wl0 = d_in[3];
    const void* bl0 = d_in[4];
    const void* Wr0 = d_in[5];
    const void* g0 = d_in[6];
    const void* be0 = d_in[7];
    const void* Wl1 = d_in[8];
    const void* bl1 = d_in[9];
    const void* Wr1 = d_in[10];
    const void* g1 = d_in[11];
    const void* be1 = d_in[12];
    const void* Wl2 = d_in[13];
    const void* bl2 = d_in[14];
    const void* Wr2 = d_in[15];
    const void* g2 = d_in[16];
    const void* be2 = d_in[17];
    const void* cW1 = d_in[18];
    const void* cb1 = d_in[19];
    const void* cW2 = d_in[20];
    const void* cb2 = d_in[21];

    const int N = in_sizes[0] / 128;  // 50000
    const int E = in_sizes[1] / 2;    // 600000
    const int G = 64;

    // workspace carve-up (256B aligned slots); ~47 MB total
    char* w = (char*)d_ws;
    size_t o = 0;
    auto take = [&](size_t bytes) -> void* {
        void* p = w + o;
        o = (o + bytes + 255) & ~(size_t)255;
        return p;
    };
    int nb1 = (N + 255) / 256;  // scan phase-1 blocks
    int* flags  = (int*)take(4 * 4);
    int* rowptr = (int*)take((size_t)(N + 1) * 4);
    int* cursor = (int*)take((size_t)N * 4);
    int* deg    = (int*)take((size_t)N * 4);
    int* bsum   = (int*)take((size_t)nb1 * 4);
    int* boff   = (int*)take((size_t)nb1 * 4);
    int* col    = (int*)take((size_t)E * 4);
    int* src32  = (int*)take((size_t)E * 4);
    int* dst32  = (int*)take((size_t)E * 4);
    int* bounds = (int*)take((size_t)(G + 1) * 4);
    float* Z    = (float*)take((size_t)G * 128 * 4);
    float* Wt0  = (float*)take((size_t)256 * 128 * 4);
    float* Wt1  = (float*)take((size_t)256 * 128 * 4);
    float* Wt2  = (float*)take((size_t)256 * 64 * 4);
    ushort_t* AGG = (ushort_t*)take((size_t)N * 128 * 2);
    ushort_t* H1  = (ushort_t*)take((size_t)N * 128 * 2);
    ushort_t* H2  = (ushort_t*)take((size_t)N * 128 * 2);
    ushort_t* XB  = H2;  // x-as-bf16 overlays H2: XB dead before H2 is first written
    ushort_t* H3  = H1;  // [N,64], reuses H1
    if (o > ws_size) return;  // ws too small -> zeros signature (diagnostic)

    int eb = (E + 255) / 256;
    k_detect<<<1, 64, 0, stream>>>(Wl0, ei, flags);
    k_zero<<<nb1, 256, 0, stream>>>(deg, Z, N);
    k_xconv<<<(N * 128 / 4 + 255) / 256, 256, 0, stream>>>(x, flags, XB, N * 128 / 4);
    k_edges<<<eb, 256, 0, stream>>>(ei, E, flags, src32, dst32);
    k_hist<<<eb, 256, 0, stream>>>(dst32, E, N, deg);
    k_scan1<<<nb1, 256, 0, stream>>>(deg, N, rowptr, bsum);
    k_scan2<<<1, 256, 0, stream>>>(bsum, nb1, boff, rowptr + N);
    k_scan3<<<nb1, 256, 0, stream>>>(rowptr, boff, cursor, N);
    k_fill<<<eb, 256, 0, stream>>>(src32, dst32, E, N, cursor, col);
    k_bounds<<<1, 128, 0, stream>>>(batch, N, G, flags, bounds);
    k_wprep<128><<<128, 256, 0, stream>>>(Wl0, Wr0, flags, Wt0);
    k_wprep<128><<<128, 256, 0, stream>>>(Wl1, Wr1, flags, Wt1);
    k_wprep<64><<<64, 256, 0, stream>>>(Wl2, Wr2, flags, Wt2);

    int gb = (N + 31) / 32;   // gemm blocks (32 rows each)
    int ab = (N + 3) / 4;     // agg blocks (4 waves = 4 nodes each)

    // layer 0: XB -> H1
    k_agg<<<ab, 256, 0, stream>>>(XB, rowptr, col, AGG, N);
    k_gemm_ln<128, 4><<<gb, 256, 0, stream>>>(AGG, XB, Wt0, bl0, g0, be0, flags, H1, N);
    // layer 1: H1 -> H2 (overwrites XB; XB dead)
    k_agg<<<ab, 256, 0, stream>>>(H1, rowptr, col, AGG, N);
    k_gemm_ln<128, 4><<<gb, 256, 0, stream>>>(AGG, H1, Wt1, bl1, g1, be1, flags, H2, N);
    // layer 2: H2 -> H3 [N,64]
    k_agg<<<ab, 256, 0, stream>>>(H2, rowptr, col, AGG, N);
    k_gemm_ln<64, 2><<<gb, 256, 0, stream>>>(AGG, H2, Wt2, bl2, g2, be2, flags, H3, N);

    k_pool<<<G * 8, 256, 0, stream>>>(H3, bounds, Z, N);
    k_mlp<<<G, 128, 0, stream>>>(Z, bounds, cW1, cb1, cW2, cb2, flags, d_out);
}

// Round 8
// 407.327 us; speedup vs baseline: 1.8820x; 1.3050x over previous
//
#include <hip/hip_runtime.h>

typedef unsigned short ushort_t;
typedef short s16x8 __attribute__((ext_vector_type(8)));
typedef float f32x4 __attribute__((ext_vector_type(4)));

#define LN_EPS 1e-5f

// ---- bf16 <-> f32 helpers ----
__device__ __forceinline__ float b2f(ushort_t u) {
    return __uint_as_float(((unsigned)u) << 16);
}
__device__ __forceinline__ ushort_t f2b(float f) {
    unsigned b = __float_as_uint(f);
    b += 0x7FFFu + ((b >> 16) & 1u);  // round-to-nearest-even
    return (ushort_t)(b >> 16);
}
// dtype-flexible load: isF ? fp32 : bf16
__device__ __forceinline__ float ldf(const void* p, size_t i, int isF) {
    return isF ? ((const float*)p)[i] : b2f(((const ushort_t*)p)[i]);
}

// harness-compat symbol (unused)
__global__ void GraphSAGE_36026185678961_kernel() {}

// ---------------- dtype detector ----------------
// flags[0]=1 if float inputs are fp32 (else bf16); flags[1]=1 if ints are int64 (else int32)
__global__ void k_detect(const void* w0, const void* ei, int* __restrict__ flags) {
    int t = threadIdx.x;  // 64 threads
    const ushort_t* u = (const ushort_t*)w0;
    int pass = 0;
    #pragma unroll
    for (int k = 0; k < 4; ++k) {
        ushort_t v = u[t * 4 + k];
        int ex = (v >> 7) & 0xFF;
        if (ex == 0 || (ex >= 0x60 && ex <= 0x7E)) pass++;  // plausible bf16 glorot value
    }
    const unsigned* w = (const unsigned*)ei;
    int nz = (w[2 * t + 1] != 0u) ? 1 : 0;  // odd words: 0 for int64 (<50000), random for int32
    #pragma unroll
    for (int off = 32; off; off >>= 1) {
        pass += __shfl_down(pass, off, 64);
        nz += __shfl_down(nz, off, 64);
    }
    if (t == 0) {
        flags[0] = (pass < 205) ? 1 : 0;  // <80% of 256 samples plausible -> fp32
        flags[1] = (nz == 0) ? 1 : 0;     // all odd words zero -> int64
    }
}

// ---------------- zero-init: deg, Z ----------------
__global__ void k_zero(int* __restrict__ deg, float* __restrict__ Z, int N) {
    int i = blockIdx.x * blockDim.x + threadIdx.x;
    if (i < N) deg[i] = 0;
    if (i < 64 * 128) Z[i] = 0.f;
}

// ---------------- x -> bf16 conversion (layer-0 input) ----------------
__global__ void k_xconv(const void* X, const int* __restrict__ flags,
                        ushort_t* __restrict__ XB, int total4) {
    int idx = blockIdx.x * blockDim.x + threadIdx.x;  // one float4/ushort4 group
    if (idx >= total4) return;
    if (flags[0]) {
        float4 v = ((const float4*)X)[idx];
        ushort4 o;
        o.x = f2b(v.x); o.y = f2b(v.y); o.z = f2b(v.z); o.w = f2b(v.w);
        ((ushort4*)XB)[idx] = o;
    } else {
        ((ushort4*)XB)[idx] = ((const ushort4*)X)[idx];
    }
}

// ---------------- edge conversion to int32 ----------------
__global__ void k_edges(const void* ei, int E, const int* __restrict__ flags,
                        int* __restrict__ s32, int* __restrict__ d32) {
    int e = blockIdx.x * blockDim.x + threadIdx.x;
    if (e >= E) return;
    if (flags[1]) {
        const long long* p = (const long long*)ei;
        s32[e] = (int)p[e];
        d32[e] = (int)p[E + e];
    } else {
        const int* p = (const int*)ei;
        s32[e] = p[e];
        d32[e] = p[E + e];
    }
}

// ---------------- CSR build ----------------
__global__ void k_hist(const int* __restrict__ dst, int E, int N, int* __restrict__ deg) {
    int e = blockIdx.x * blockDim.x + threadIdx.x;
    if (e < E) {
        int d = dst[e];
        if ((unsigned)d < (unsigned)N) atomicAdd(&deg[d], 1);
    }
}

// hierarchical scan, phase 1: per-block (256-elem) exclusive scan + block totals
__global__ void k_scan1(const int* __restrict__ deg, int N,
                        int* __restrict__ rowptr, int* __restrict__ bsum) {
    __shared__ int wsum[4];
    __shared__ int wpre[4];
    int tid = threadIdx.x;
    int lane = tid & 63;
    int w = tid >> 6;
    int i = blockIdx.x * 256 + tid;
    int v = (i < N) ? deg[i] : 0;
    int x = v;
    #pragma unroll
    for (int off = 1; off < 64; off <<= 1) {
        int t = __shfl_up(x, off, 64);
        if (lane >= off) x += t;
    }
    if (lane == 63) wsum[w] = x;
    __syncthreads();
    if (tid == 0) {
        int a = wsum[0]; wpre[0] = a;
        a += wsum[1]; wpre[1] = a;
        a += wsum[2]; wpre[2] = a;
        a += wsum[3]; wpre[3] = a;
    }
    __syncthreads();
    int woff = (w == 0) ? 0 : wpre[w - 1];
    if (i < N) rowptr[i] = woff + x - v;  // block-local exclusive
    if (tid == 0) bsum[blockIdx.x] = wpre[3];
}

// phase 2: single-block exclusive scan of block sums
__global__ void k_scan2(const int* __restrict__ bsum, int nb,
                        int* __restrict__ boff, int* __restrict__ rowptrN) {
    __shared__ int wsum[4];
    __shared__ int wpre[4];
    int tid = threadIdx.x;
    int lane = tid & 63;
    int w = tid >> 6;
    int run = 0;
    for (int base = 0; base < nb; base += 256) {
        int i = base + tid;
        int v = (i < nb) ? bsum[i] : 0;
        int x = v;
        #pragma unroll
        for (int off = 1; off < 64; off <<= 1) {
            int t = __shfl_up(x, off, 64);
            if (lane >= off) x += t;
        }
        if (lane == 63) wsum[w] = x;
        __syncthreads();
        if (tid == 0) {
            int a = wsum[0]; wpre[0] = a;
            a += wsum[1]; wpre[1] = a;
            a += wsum[2]; wpre[2] = a;
            a += wsum[3]; wpre[3] = a;
        }
        __syncthreads();
        int woff = (w == 0) ? 0 : wpre[w - 1];
        if (i < nb) boff[i] = run + woff + x - v;
        int tot = wpre[3];
        __syncthreads();
        run += tot;
    }
    if (tid == 0) *rowptrN = run;  // rowptr[N] = E_total
}

// phase 3: add block offsets; produce cursor copy
__global__ void k_scan3(int* __restrict__ rowptr, const int* __restrict__ boff,
                        int* __restrict__ cursor, int N) {
    int i = blockIdx.x * 256 + threadIdx.x;
    if (i < N) {
        int r = rowptr[i] + boff[i >> 8];
        rowptr[i] = r;
        cursor[i] = r;
    }
}

__global__ void k_fill(const int* __restrict__ src, const int* __restrict__ dst, int E, int N,
                       int* __restrict__ cursor, int* __restrict__ col) {
    int e = blockIdx.x * blockDim.x + threadIdx.x;
    if (e < E) {
        int d = dst[e];
        if ((unsigned)d < (unsigned)N) {
            int p = atomicAdd(&cursor[d], 1);
            if ((unsigned)p < (unsigned)E) {
                int s = src[e];
                col[p] = ((unsigned)s < (unsigned)N) ? s : 0;
            }
        }
    }
}

__global__ void k_bounds(const void* batch, int N, int G, const int* __restrict__ flags,
                         int* __restrict__ bounds) {
    int g = threadIdx.x;
    if (g > G) return;
    int isL = flags[1];
    int lo = 0, hi = N;
    while (lo < hi) {
        int mid = (lo + hi) >> 1;
        int bv = isL ? (int)((const long long*)batch)[mid] : ((const int*)batch)[mid];
        if (bv < g) lo = mid + 1; else hi = mid;
    }
    bounds[g] = lo;
}

// ---------------- mean aggregation: AGG[i] = mean_{j in N(i)} X[j]  (bf16, 128-wide) ----------------
__global__ __launch_bounds__(256) void k_agg(
    const ushort_t* __restrict__ X, const int* __restrict__ rowptr,
    const int* __restrict__ col, ushort_t* __restrict__ AGG, int N) {
    int i = blockIdx.x * 4 + (threadIdx.x >> 6);
    if (i >= N) return;
    int l = threadIdx.x & 63;
    const ushort2* X2 = (const ushort2*)X;
    int s = rowptr[i], e = rowptr[i + 1];
    float a0 = 0.f, b0 = 0.f, a1 = 0.f, b1 = 0.f;
    int p = s;
    for (; p + 4 <= e; p += 4) {
        int j0 = col[p], j1 = col[p + 1], j2 = col[p + 2], j3 = col[p + 3];
        ushort2 u0 = X2[(size_t)j0 * 64 + l];
        ushort2 u1 = X2[(size_t)j1 * 64 + l];
        ushort2 u2 = X2[(size_t)j2 * 64 + l];
        ushort2 u3 = X2[(size_t)j3 * 64 + l];
        a0 += b2f(u0.x); b0 += b2f(u0.y);
        a1 += b2f(u1.x); b1 += b2f(u1.y);
        a0 += b2f(u2.x); b0 += b2f(u2.y);
        a1 += b2f(u3.x); b1 += b2f(u3.y);
    }
    for (; p < e; ++p) {
        int j = col[p];
        ushort2 u = X2[(size_t)j * 64 + l];
        a0 += b2f(u.x); b0 += b2f(u.y);
    }
    int d = e - s;
    float inv = 1.f / (float)(d > 0 ? d : 1);
    ushort2 o;
    o.x = f2b((a0 + a1) * inv);
    o.y = f2b((b0 + b1) * inv);
    ((ushort2*)AGG)[(size_t)i * 64 + l] = o;
}

// ---------------- weight prep: Wb[f][k] bf16, k<128 -> Wl[f][k], k>=128 -> Wr[f][k-128] ----------------
template <int FO>
__global__ void k_wprep(const void* Wl, const void* Wr, const int* __restrict__ flags,
                        ushort_t* __restrict__ Wb) {
    int t = blockIdx.x * blockDim.x + threadIdx.x;
    if (t >= 256 * FO) return;
    int isF = flags[0];
    int f = t >> 8, k = t & 255;
    float v = (k < 128) ? ldf(Wl, f * 128 + k, isF) : ldf(Wr, f * 128 + (k - 128), isF);
    Wb[t] = isF ? f2b(v) : ((const ushort_t*)((k < 128) ? Wl : Wr))[f * 128 + (k & 127)];
}

// ---------------- fused MFMA GEMM + bias + LayerNorm + ReLU ----------------
// H = relu(LN([AGG|X] @ Wb^T + bl) * gam + bet), all bf16 inputs, fp32 acc.
// One wave: 16 rows x FO cols via mfma_f32_16x16x32_bf16, K=256 in 8 steps.
// A-frag: A[m=lane&15][k=q*8+j] -> 16B contiguous loads from AGG/X rows.
// B-frag: B[k=q*8+j][n=lane&15] -> 16B contiguous loads from Wb[n][k...].
// C/D: col=lane&15, row=q*4+reg.
template <int FO>
__global__ __launch_bounds__(256) void k_gemm_ln(
    const ushort_t* __restrict__ AGG, const ushort_t* __restrict__ X,
    const ushort_t* __restrict__ Wb,  // [FO][256] bf16
    const void* bl, const void* gam, const void* bet,
    const int* __restrict__ flags,
    ushort_t* __restrict__ H, int M) {
    constexpr int NT = FO / 16;
    int lane = threadIdx.x & 63;
    int wid = threadIdx.x >> 6;
    int row0 = (blockIdx.x * 4 + wid) * 16;
    if (row0 >= M) return;
    int isF = flags[0];
    int m = lane & 15;
    int q = lane >> 4;

    int arow = row0 + m;
    if (arow >= M) arow = M - 1;  // tail clamp (stores guarded below)
    const ushort_t* aA = AGG + (size_t)arow * 128 + q * 8;
    const ushort_t* aX = X + (size_t)arow * 128 + q * 8;
    const ushort_t* bW = Wb + (size_t)m * 256 + q * 8;  // col n=m, advance by nt*16 rows

    f32x4 acc[NT];
    #pragma unroll
    for (int nt = 0; nt < NT; ++nt) acc[nt] = (f32x4){0.f, 0.f, 0.f, 0.f};

    #pragma unroll
    for (int kk = 0; kk < 4; ++kk) {  // first half: AGG columns k=0..127
        s16x8 a = *(const s16x8*)(aA + kk * 32);
        #pragma unroll
        for (int nt = 0; nt < NT; ++nt) {
            s16x8 b = *(const s16x8*)(bW + (size_t)nt * 16 * 256 + kk * 32);
            acc[nt] = __builtin_amdgcn_mfma_f32_16x16x32_bf16(a, b, acc[nt], 0, 0, 0);
        }
    }
    #pragma unroll
    for (int kk = 0; kk < 4; ++kk) {  // second half: X columns k=128..255
        s16x8 a = *(const s16x8*)(aX + kk * 32);
        #pragma unroll
        for (int nt = 0; nt < NT; ++nt) {
            s16x8 b = *(const s16x8*)(bW + (size_t)nt * 16 * 256 + 128 + kk * 32);
            acc[nt] = __builtin_amdgcn_mfma_f32_16x16x32_bf16(a, b, acc[nt], 0, 0, 0);
        }
    }

    // bias (indexed by col = nt*16 + m)
    #pragma unroll
    for (int nt = 0; nt < NT; ++nt) {
        float bv = ldf(bl, nt * 16 + m, isF);
        #pragma unroll
        for (int r = 0; r < 4; ++r) acc[nt][r] += bv;
    }

    // LayerNorm stats per row (row = q*4 + r): cols live in 16 lanes (same q) x NT regs
    float mu[4], rs[4];
    #pragma unroll
    for (int r = 0; r < 4; ++r) {
        float s1 = 0.f, s2 = 0.f;
        #pragma unroll
        for (int nt = 0; nt < NT; ++nt) {
            float v = acc[nt][r];
            s1 += v;
            s2 += v * v;
        }
        #pragma unroll
        for (int off = 1; off < 16; off <<= 1) {
            s1 += __shfl_xor(s1, off, 64);
            s2 += __shfl_xor(s2, off, 64);
        }
        float mm = s1 / (float)FO;
        float var = s2 / (float)FO - mm * mm;
        var = var > 0.f ? var : 0.f;
        mu[r] = mm;
        rs[r] = rsqrtf(var + LN_EPS);
    }

    #pragma unroll
    for (int nt = 0; nt < NT; ++nt) {
        int n0 = nt * 16 + m;
        float g = ldf(gam, n0, isF);
        float be = ldf(bet, n0, isF);
        #pragma unroll
        for (int r = 0; r < 4; ++r) {
            int row = row0 + q * 4 + r;
            if (row < M) {
                float y = (acc[nt][r] - mu[r]) * rs[r] * g + be;
                y = y > 0.f ? y : 0.f;
                H[(size_t)row * FO + n0] = f2b(y);
            }
        }
    }
}

// ---------------- pooling: Z[64][128]: cols 0..63 sum, 64..127 max ----------------
__global__ void k_pool(const ushort_t* __restrict__ H,  // [N,64], post-ReLU (>=0)
                       const int* __restrict__ bounds, float* __restrict__ Z, int N) {
    int g = blockIdx.x >> 3;
    int chunk = blockIdx.x & 7;
    int f = threadIdx.x & 63;
    int sub = threadIdx.x >> 6;
    int strm = chunk * 4 + sub;
    int s = bounds[g], e = bounds[g + 1];
    s = s < 0 ? 0 : (s > N ? N : s);
    e = e < s ? s : (e > N ? N : e);
    float sum = 0.f, mx = 0.f;
    for (int i = s + strm; i < e; i += 32) {
        float v = b2f(H[(size_t)i * 64 + f]);
        sum += v;
        mx = mx > v ? mx : v;
    }
    atomicAdd(&Z[g * 128 + f], sum);
    atomicMax((int*)&Z[g * 128 + 64 + f], __float_as_int(mx));
}

// ---------------- final MLP; output dtype follows flags[0] ----------------
__global__ void k_mlp(const float* __restrict__ Z, const int* __restrict__ bounds,
                      const void* cW1, const void* cb1, const void* cW2, const void* cb2,
                      const int* __restrict__ flags, void* __restrict__ out) {
    int g = blockIdx.x;
    int f = threadIdx.x;  // 0..127
    int isF = flags[0];
    __shared__ float z[128];
    __shared__ float hid[128];
    __shared__ float r0[2], r1[2];
    int cnt = bounds[g + 1] - bounds[g];
    float c = (float)(cnt > 0 ? cnt : 1);
    float zv = Z[g * 128 + f];
    if (f < 64) zv /= c;
    z[f] = zv;
    __syncthreads();
    float acc = ldf(cb1, f, isF);
    #pragma unroll 8
    for (int k = 0; k < 128; ++k) acc += z[k] * ldf(cW1, f * 128 + k, isF);
    acc = acc > 0.f ? acc : 0.f;
    hid[f] = acc;
    __syncthreads();
    float p0 = hid[f] * ldf(cW2, f, isF);
    float p1 = hid[f] * ldf(cW2, 128 + f, isF);
    #pragma unroll
    for (int off = 32; off > 0; off >>= 1) {
        p0 += __shfl_xor(p0, off, 64);
        p1 += __shfl_xor(p1, off, 64);
    }
    int w = f >> 6;
    if ((f & 63) == 0) { r0[w] = p0; r1[w] = p1; }
    __syncthreads();
    if (f == 0) {
        float v0 = r0[0] + r0[1] + ldf(cb2, 0, isF);
        float v1 = r1[0] + r1[1] + ldf(cb2, 1, isF);
        if (isF) {
            ((float*)out)[g * 2 + 0] = v0;
            ((float*)out)[g * 2 + 1] = v1;
        } else {
            ((ushort_t*)out)[g * 2 + 0] = f2b(v0);
            ((ushort_t*)out)[g * 2 + 1] = f2b(v1);
        }
    }
}

// ---------------- launch ----------------
extern "C" void kernel_launch(void* const* d_in, const int* in_sizes, int n_in,
                              void* d_out, int out_size, void* d_ws, size_t ws_size,
                              hipStream_t stream) {
    const void* x = d_in[0];
    const void* ei = d_in[1];
    const void* batch = d_in[2];
    const void* Wl0 = d_in[3];
    const void* bl0 = d_in[4];
    const void* Wr0 = d_in[5];
    const void* g0 = d_in[6];
    const void* be0 = d_in[7];
    const void* Wl1 = d_in[8];
    const void* bl1 = d_in[9];
    const void* Wr1 = d_in[10];
    const void* g1 = d_in[11];
    const void* be1 = d_in[12];
    const void* Wl2 = d_in[13];
    const void* bl2 = d_in[14];
    const void* Wr2 = d_in[15];
    const void* g2 = d_in[16];
    const void* be2 = d_in[17];
    const void* cW1 = d_in[18];
    const void* cb1 = d_in[19];
    const void* cW2 = d_in[20];
    const void* cb2 = d_in[21];

    const int N = in_sizes[0] / 128;  // 50000
    const int E = in_sizes[1] / 2;    // 600000
    const int G = 64;

    // workspace carve-up (256B aligned slots)
    char* w = (char*)d_ws;
    size_t o = 0;
    auto take = [&](size_t bytes) -> void* {
        void* p = w + o;
        o = (o + bytes + 255) & ~(size_t)255;
        return p;
    };
    int nb1 = (N + 255) / 256;  // scan phase-1 blocks
    int* flags  = (int*)take(4 * 4);
    int* rowptr = (int*)take((size_t)(N + 1) * 4);
    int* cursor = (int*)take((size_t)N * 4);
    int* deg    = (int*)take((size_t)N * 4);
    int* bsum   = (int*)take((size_t)nb1 * 4);
    int* boff   = (int*)take((size_t)nb1 * 4);
    int* col    = (int*)take((size_t)E * 4);
    int* src32  = (int*)take((size_t)E * 4);
    int* dst32  = (int*)take((size_t)E * 4);
    int* bounds = (int*)take((size_t)(G + 1) * 4);
    float* Z    = (float*)take((size_t)G * 128 * 4);
    ushort_t* Wb0 = (ushort_t*)take((size_t)128 * 256 * 2);
    ushort_t* Wb1 = (ushort_t*)take((size_t)128 * 256 * 2);
    ushort_t* Wb2 = (ushort_t*)take((size_t)64 * 256 * 2);
    ushort_t* AGG = (ushort_t*)take((size_t)N * 128 * 2);
    ushort_t* H1  = (ushort_t*)take((size_t)N * 128 * 2);
    ushort_t* H2  = (ushort_t*)take((size_t)N * 128 * 2);
    ushort_t* XB  = H2;  // x-as-bf16 overlays H2: XB dead before H2 is first written
    ushort_t* H3  = H1;  // [N,64], reuses H1
    if (o > ws_size) return;  // ws too small -> zeros signature (diagnostic)

    int eb = (E + 255) / 256;
    k_detect<<<1, 64, 0, stream>>>(Wl0, ei, flags);
    k_zero<<<nb1, 256, 0, stream>>>(deg, Z, N);
    k_xconv<<<(N * 128 / 4 + 255) / 256, 256, 0, stream>>>(x, flags, XB, N * 128 / 4);
    k_edges<<<eb, 256, 0, stream>>>(ei, E, flags, src32, dst32);
    k_hist<<<eb, 256, 0, stream>>>(dst32, E, N, deg);
    k_scan1<<<nb1, 256, 0, stream>>>(deg, N, rowptr, bsum);
    k_scan2<<<1, 256, 0, stream>>>(bsum, nb1, boff, rowptr + N);
    k_scan3<<<nb1, 256, 0, stream>>>(rowptr, boff, cursor, N);
    k_fill<<<eb, 256, 0, stream>>>(src32, dst32, E, N, cursor, col);
    k_bounds<<<1, 128, 0, stream>>>(batch, N, G, flags, bounds);
    k_wprep<128><<<128, 256, 0, stream>>>(Wl0, Wr0, flags, Wb0);
    k_wprep<128><<<128, 256, 0, stream>>>(Wl1, Wr1, flags, Wb1);
    k_wprep<64><<<64, 256, 0, stream>>>(Wl2, Wr2, flags, Wb2);

    int gb = (N + 63) / 64;   // gemm blocks (4 waves x 16 rows)
    int ab = (N + 3) / 4;     // agg blocks (4 waves = 4 nodes each)

    // layer 0: XB -> H1
    k_agg<<<ab, 256, 0, stream>>>(XB, rowptr, col, AGG, N);
    k_gemm_ln<128><<<gb, 256, 0, stream>>>(AGG, XB, Wb0, bl0, g0, be0, flags, H1, N);
    // layer 1: H1 -> H2 (overwrites XB; XB dead)
    k_agg<<<ab, 256, 0, stream>>>(H1, rowptr, col, AGG, N);
    k_gemm_ln<128><<<gb, 256, 0, stream>>>(AGG, H1, Wb1, bl1, g1, be1, flags, H2, N);
    // layer 2: H2 -> H3 [N,64]
    k_agg<<<ab, 256, 0, stream>>>(H2, rowptr, col, AGG, N);
    k_gemm_ln<64><<<gb, 256, 0, stream>>>(AGG, H2, Wb2, bl2, g2, be2, flags, H3, N);

    k_pool<<<G * 8, 256, 0, stream>>>(H3, bounds, Z, N);
    k_mlp<<<G, 128, 0, stream>>>(Z, bounds, cW1, cb1, cW2, cb2, flags, d_out);
}

// Round 9
// 393.088 us; speedup vs baseline: 1.9501x; 1.0362x over previous
//
#include <hip/hip_runtime.h>

typedef unsigned short ushort_t;
typedef short s16x8 __attribute__((ext_vector_type(8)));
typedef float f32x4 __attribute__((ext_vector_type(4)));

#define LN_EPS 1e-5f

// ---- bf16 <-> f32 helpers ----
__device__ __forceinline__ float b2f(ushort_t u) {
    return __uint_as_float(((unsigned)u) << 16);
}
__device__ __forceinline__ ushort_t f2b(float f) {
    unsigned b = __float_as_uint(f);
    b += 0x7FFFu + ((b >> 16) & 1u);  // round-to-nearest-even
    return (ushort_t)(b >> 16);
}
// dtype-flexible load: isF ? fp32 : bf16
__device__ __forceinline__ float ldf(const void* p, size_t i, int isF) {
    return isF ? ((const float*)p)[i] : b2f(((const ushort_t*)p)[i]);
}

// harness-compat symbol (unused)
__global__ void GraphSAGE_36026185678961_kernel() {}

// ---------------- dtype detector ----------------
// flags[0]=1 if float inputs are fp32 (else bf16); flags[1]=1 if ints are int64 (else int32)
__global__ void k_detect(const void* w0, const void* ei, int* __restrict__ flags) {
    int t = threadIdx.x;  // 64 threads
    const ushort_t* u = (const ushort_t*)w0;
    int pass = 0;
    #pragma unroll
    for (int k = 0; k < 4; ++k) {
        ushort_t v = u[t * 4 + k];
        int ex = (v >> 7) & 0xFF;
        if (ex == 0 || (ex >= 0x60 && ex <= 0x7E)) pass++;  // plausible bf16 glorot value
    }
    const unsigned* w = (const unsigned*)ei;
    int nz = (w[2 * t + 1] != 0u) ? 1 : 0;  // odd words: 0 for int64 (<50000), random for int32
    #pragma unroll
    for (int off = 32; off; off >>= 1) {
        pass += __shfl_down(pass, off, 64);
        nz += __shfl_down(nz, off, 64);
    }
    if (t == 0) {
        flags[0] = (pass < 205) ? 1 : 0;  // <80% of 256 samples plausible -> fp32
        flags[1] = (nz == 0) ? 1 : 0;     // all odd words zero -> int64
    }
}

// ---------------- zero-init: deg, Z ----------------
__global__ void k_zero(int* __restrict__ deg, float* __restrict__ Z, int N) {
    int i = blockIdx.x * blockDim.x + threadIdx.x;
    if (i < N) deg[i] = 0;
    if (i < 64 * 128) Z[i] = 0.f;
}

// ---------------- x -> bf16 conversion (layer-0 input) ----------------
__global__ void k_xconv(const void* X, const int* __restrict__ flags,
                        ushort_t* __restrict__ XB, int total4) {
    int idx = blockIdx.x * blockDim.x + threadIdx.x;
    if (idx >= total4) return;
    if (flags[0]) {
        float4 v = ((const float4*)X)[idx];
        ushort4 o;
        o.x = f2b(v.x); o.y = f2b(v.y); o.z = f2b(v.z); o.w = f2b(v.w);
        ((ushort4*)XB)[idx] = o;
    } else {
        ((ushort4*)XB)[idx] = ((const ushort4*)X)[idx];
    }
}

// ---------------- edge conversion to int32 + degree histogram (fused) ----------------
__global__ void k_edges(const void* ei, int E, int N, const int* __restrict__ flags,
                        int* __restrict__ s32, int* __restrict__ d32, int* __restrict__ deg) {
    int e = blockIdx.x * blockDim.x + threadIdx.x;
    if (e >= E) return;
    int s, d;
    if (flags[1]) {
        const long long* p = (const long long*)ei;
        s = (int)p[e];
        d = (int)p[E + e];
    } else {
        const int* p = (const int*)ei;
        s = p[e];
        d = p[E + e];
    }
    s32[e] = s;
    d32[e] = d;
    if ((unsigned)d < (unsigned)N) atomicAdd(&deg[d], 1);
}

// hierarchical scan, phase 1: per-block (256-elem) exclusive scan + block totals
__global__ void k_scan1(const int* __restrict__ deg, int N,
                        int* __restrict__ rowptr, int* __restrict__ bsum) {
    __shared__ int wsum[4];
    __shared__ int wpre[4];
    int tid = threadIdx.x;
    int lane = tid & 63;
    int w = tid >> 6;
    int i = blockIdx.x * 256 + tid;
    int v = (i < N) ? deg[i] : 0;
    int x = v;
    #pragma unroll
    for (int off = 1; off < 64; off <<= 1) {
        int t = __shfl_up(x, off, 64);
        if (lane >= off) x += t;
    }
    if (lane == 63) wsum[w] = x;
    __syncthreads();
    if (tid == 0) {
        int a = wsum[0]; wpre[0] = a;
        a += wsum[1]; wpre[1] = a;
        a += wsum[2]; wpre[2] = a;
        a += wsum[3]; wpre[3] = a;
    }
    __syncthreads();
    int woff = (w == 0) ? 0 : wpre[w - 1];
    if (i < N) rowptr[i] = woff + x - v;  // block-local exclusive
    if (tid == 0) bsum[blockIdx.x] = wpre[3];
}

// phase 2: single-block exclusive scan of block sums
__global__ void k_scan2(const int* __restrict__ bsum, int nb,
                        int* __restrict__ boff, int* __restrict__ rowptrN) {
    __shared__ int wsum[4];
    __shared__ int wpre[4];
    int tid = threadIdx.x;
    int lane = tid & 63;
    int w = tid >> 6;
    int run = 0;
    for (int base = 0; base < nb; base += 256) {
        int i = base + tid;
        int v = (i < nb) ? bsum[i] : 0;
        int x = v;
        #pragma unroll
        for (int off = 1; off < 64; off <<= 1) {
            int t = __shfl_up(x, off, 64);
            if (lane >= off) x += t;
        }
        if (lane == 63) wsum[w] = x;
        __syncthreads();
        if (tid == 0) {
            int a = wsum[0]; wpre[0] = a;
            a += wsum[1]; wpre[1] = a;
            a += wsum[2]; wpre[2] = a;
            a += wsum[3]; wpre[3] = a;
        }
        __syncthreads();
        int woff = (w == 0) ? 0 : wpre[w - 1];
        if (i < nb) boff[i] = run + woff + x - v;
        int tot = wpre[3];
        __syncthreads();
        run += tot;
    }
    if (tid == 0) *rowptrN = run;  // rowptr[N] = E_total
}

// phase 3: add block offsets; produce cursor copy
__global__ void k_scan3(int* __restrict__ rowptr, const int* __restrict__ boff,
                        int* __restrict__ cursor, int N) {
    int i = blockIdx.x * 256 + threadIdx.x;
    if (i < N) {
        int r = rowptr[i] + boff[i >> 8];
        rowptr[i] = r;
        cursor[i] = r;
    }
}

__global__ void k_fill(const int* __restrict__ src, const int* __restrict__ dst, int E, int N,
                       int* __restrict__ cursor, int* __restrict__ col) {
    int e = blockIdx.x * blockDim.x + threadIdx.x;
    if (e < E) {
        int d = dst[e];
        if ((unsigned)d < (unsigned)N) {
            int p = atomicAdd(&cursor[d], 1);
            if ((unsigned)p < (unsigned)E) {
                int s = src[e];
                col[p] = ((unsigned)s < (unsigned)N) ? s : 0;
            }
        }
    }
}

__global__ void k_bounds(const void* batch, int N, int G, const int* __restrict__ flags,
                         int* __restrict__ bounds) {
    int g = threadIdx.x;
    if (g > G) return;
    int isL = flags[1];
    int lo = 0, hi = N;
    while (lo < hi) {
        int mid = (lo + hi) >> 1;
        int bv = isL ? (int)((const long long*)batch)[mid] : ((const int*)batch)[mid];
        if (bv < g) lo = mid + 1; else hi = mid;
    }
    bounds[g] = lo;
}

// ---------------- mean aggregation: AGG[i] = mean_{j in N(i)} X[j]  (bf16, 128-wide) ----------------
// one wave per node; lane-half 0 (lanes 0-31) handles even neighbors, half 1 odd neighbors;
// each lane loads ushort4 (8B) -> 2 neighbor-rows per wave gather instruction.
__global__ __launch_bounds__(256) void k_agg(
    const ushort_t* __restrict__ X, const int* __restrict__ rowptr,
    const int* __restrict__ col, ushort_t* __restrict__ AGG, int N) {
    int i = blockIdx.x * 4 + (threadIdx.x >> 6);
    if (i >= N) return;
    int l = threadIdx.x & 63;
    int half = l >> 5;   // which neighbor of a pair
    int fq = l & 31;     // feature quad: feats 4*fq..4*fq+3
    const ushort4* X4 = (const ushort4*)X;  // row stride 32 quads
    int s = rowptr[i], e = rowptr[i + 1];
    float a0 = 0.f, a1 = 0.f, a2 = 0.f, a3 = 0.f;
    int p = s + half;
    for (; p + 2 < e; p += 4) {  // 2 neighbors/lane/iter (4 across wave-halves)
        int j0 = col[p], j1 = col[p + 2];
        ushort4 u0 = X4[(size_t)j0 * 32 + fq];
        ushort4 u1 = X4[(size_t)j1 * 32 + fq];
        a0 += b2f(u0.x) + b2f(u1.x);
        a1 += b2f(u0.y) + b2f(u1.y);
        a2 += b2f(u0.z) + b2f(u1.z);
        a3 += b2f(u0.w) + b2f(u1.w);
    }
    for (; p < e; p += 2) {
        int j = col[p];
        ushort4 u = X4[(size_t)j * 32 + fq];
        a0 += b2f(u.x); a1 += b2f(u.y); a2 += b2f(u.z); a3 += b2f(u.w);
    }
    // combine halves
    a0 += __shfl_xor(a0, 32, 64);
    a1 += __shfl_xor(a1, 32, 64);
    a2 += __shfl_xor(a2, 32, 64);
    a3 += __shfl_xor(a3, 32, 64);
    if (half == 0) {
        int d = e - s;
        float inv = 1.f / (float)(d > 0 ? d : 1);
        ushort4 o;
        o.x = f2b(a0 * inv);
        o.y = f2b(a1 * inv);
        o.z = f2b(a2 * inv);
        o.w = f2b(a3 * inv);
        ((ushort4*)AGG)[(size_t)i * 32 + fq] = o;
    }
}

// ---------------- weight prep: Wb[f][k] bf16 ----------------
template <int FO>
__global__ void k_wprep(const void* Wl, const void* Wr, const int* __restrict__ flags,
                        ushort_t* __restrict__ Wb) {
    int t = blockIdx.x * blockDim.x + threadIdx.x;
    if (t >= 256 * FO) return;
    int isF = flags[0];
    int f = t >> 8, k = t & 255;
    float v = (k < 128) ? ldf(Wl, f * 128 + k, isF) : ldf(Wr, f * 128 + (k - 128), isF);
    Wb[t] = isF ? f2b(v) : ((const ushort_t*)((k < 128) ? Wl : Wr))[f * 128 + (k & 127)];
}

// ---------------- fused MFMA GEMM + bias + LayerNorm + ReLU ----------------
// H = relu(LN([AGG|X] @ Wb^T + bl) * gam + bet), bf16 in, fp32 acc.
// One wave: R=4 row-tiles (64 rows) x FO cols; B-frag loaded once per (kk,nt), reused x4.
// A-frag: A[m=lane&15][k=q*8+j]; B-frag: B[k][n=lane&15]; C/D: col=lane&15, row=q*4+reg.
template <int FO>
__global__ __launch_bounds__(256, 1) void k_gemm_ln(
    const ushort_t* __restrict__ AGG, const ushort_t* __restrict__ X,
    const ushort_t* __restrict__ Wb,  // [FO][256] bf16
    const void* bl, const void* gam, const void* bet,
    const int* __restrict__ flags,
    ushort_t* __restrict__ H, int M) {
    constexpr int NT = FO / 16;
    constexpr int R = 4;
    int lane = threadIdx.x & 63;
    int wid = threadIdx.x >> 6;
    int wrow0 = (blockIdx.x * 4 + wid) * (R * 16);
    if (wrow0 >= M) return;
    int isF = flags[0];
    int m = lane & 15;
    int q = lane >> 4;

    int arow[R];
    #pragma unroll
    for (int r = 0; r < R; ++r) {
        int ar = wrow0 + r * 16 + m;
        arow[r] = (ar < M) ? ar : (M - 1);  // tail clamp; stores guarded below
    }

    f32x4 acc[R][NT];
    #pragma unroll
    for (int r = 0; r < R; ++r)
        #pragma unroll
        for (int nt = 0; nt < NT; ++nt) acc[r][nt] = (f32x4){0.f, 0.f, 0.f, 0.f};

    #pragma unroll
    for (int kk = 0; kk < 8; ++kk) {
        const ushort_t* base = (kk < 4) ? AGG : X;
        int ko = (kk & 3) * 32 + q * 8;
        s16x8 a[R];
        #pragma unroll
        for (int r = 0; r < R; ++r)
            a[r] = *(const s16x8*)(base + (size_t)arow[r] * 128 + ko);
        #pragma unroll
        for (int nt = 0; nt < NT; ++nt) {
            s16x8 b = *(const s16x8*)(Wb + (size_t)(nt * 16 + m) * 256 + kk * 32 + q * 8);
            #pragma unroll
            for (int r = 0; r < R; ++r)
                acc[r][nt] = __builtin_amdgcn_mfma_f32_16x16x32_bf16(a[r], b, acc[r][nt], 0, 0, 0);
        }
    }

    // epilogue per row-tile: bias + LN + ReLU + store
    #pragma unroll
    for (int r = 0; r < R; ++r) {
        #pragma unroll
        for (int nt = 0; nt < NT; ++nt) {
            float bv = ldf(bl, nt * 16 + m, isF);
            #pragma unroll
            for (int rr = 0; rr < 4; ++rr) acc[r][nt][rr] += bv;
        }
        float mu[4], rs[4];
        #pragma unroll
        for (int rr = 0; rr < 4; ++rr) {
            float s1 = 0.f, s2 = 0.f;
            #pragma unroll
            for (int nt = 0; nt < NT; ++nt) {
                float v = acc[r][nt][rr];
                s1 += v;
                s2 += v * v;
            }
            #pragma unroll
            for (int off = 1; off < 16; off <<= 1) {
                s1 += __shfl_xor(s1, off, 64);
                s2 += __shfl_xor(s2, off, 64);
            }
            float mm = s1 / (float)FO;
            float var = s2 / (float)FO - mm * mm;
            var = var > 0.f ? var : 0.f;
            mu[rr] = mm;
            rs[rr] = rsqrtf(var + LN_EPS);
        }
        #pragma unroll
        for (int nt = 0; nt < NT; ++nt) {
            int n0 = nt * 16 + m;
            float g = ldf(gam, n0, isF);
            float be = ldf(bet, n0, isF);
            #pragma unroll
            for (int rr = 0; rr < 4; ++rr) {
                int row = wrow0 + r * 16 + q * 4 + rr;
                if (row < M) {
                    float y = (acc[r][nt][rr] - mu[rr]) * rs[rr] * g + be;
                    y = y > 0.f ? y : 0.f;
                    H[(size_t)row * FO + n0] = f2b(y);
                }
            }
        }
    }
}

// ---------------- pooling: Z[64][128]: cols 0..63 sum, 64..127 max ----------------
__global__ void k_pool(const ushort_t* __restrict__ H,  // [N,64], post-ReLU (>=0)
                       const int* __restrict__ bounds, float* __restrict__ Z, int N) {
    int g = blockIdx.x >> 3;
    int chunk = blockIdx.x & 7;
    int f = threadIdx.x & 63;
    int sub = threadIdx.x >> 6;
    int strm = chunk * 4 + sub;
    int s = bounds[g], e = bounds[g + 1];
    s = s < 0 ? 0 : (s > N ? N : s);
    e = e < s ? s : (e > N ? N : e);
    float sum = 0.f, mx = 0.f;
    for (int i = s + strm; i < e; i += 32) {
        float v = b2f(H[(size_t)i * 64 + f]);
        sum += v;
        mx = mx > v ? mx : v;
    }
    atomicAdd(&Z[g * 128 + f], sum);
    atomicMax((int*)&Z[g * 128 + 64 + f], __float_as_int(mx));
}

// ---------------- final MLP; output dtype follows flags[0] ----------------
__global__ void k_mlp(const float* __restrict__ Z, const int* __restrict__ bounds,
                      const void* cW1, const void* cb1, const void* cW2, const void* cb2,
                      const int* __restrict__ flags, void* __restrict__ out) {
    int g = blockIdx.x;
    int f = threadIdx.x;  // 0..127
    int isF = flags[0];
    __shared__ float z[128];
    __shared__ float hid[128];
    __shared__ float r0[2], r1[2];
    int cnt = bounds[g + 1] - bounds[g];
    float c = (float)(cnt > 0 ? cnt : 1);
    float zv = Z[g * 128 + f];
    if (f < 64) zv /= c;
    z[f] = zv;
    __syncthreads();
    float acc = ldf(cb1, f, isF);
    #pragma unroll 8
    for (int k = 0; k < 128; ++k) acc += z[k] * ldf(cW1, f * 128 + k, isF);
    acc = acc > 0.f ? acc : 0.f;
    hid[f] = acc;
    __syncthreads();
    float p0 = hid[f] * ldf(cW2, f, isF);
    float p1 = hid[f] * ldf(cW2, 128 + f, isF);
    #pragma unroll
    for (int off = 32; off > 0; off >>= 1) {
        p0 += __shfl_xor(p0, off, 64);
        p1 += __shfl_xor(p1, off, 64);
    }
    int w = f >> 6;
    if ((f & 63) == 0) { r0[w] = p0; r1[w] = p1; }
    __syncthreads();
    if (f == 0) {
        float v0 = r0[0] + r0[1] + ldf(cb2, 0, isF);
        float v1 = r1[0] + r1[1] + ldf(cb2, 1, isF);
        if (isF) {
            ((float*)out)[g * 2 + 0] = v0;
            ((float*)out)[g * 2 + 1] = v1;
        } else {
            ((ushort_t*)out)[g * 2 + 0] = f2b(v0);
            ((ushort_t*)out)[g * 2 + 1] = f2b(v1);
        }
    }
}

// ---------------- launch ----------------
extern "C" void kernel_launch(void* const* d_in, const int* in_sizes, int n_in,
                              void* d_out, int out_size, void* d_ws, size_t ws_size,
                              hipStream_t stream) {
    const void* x = d_in[0];
    const void* ei = d_in[1];
    const void* batch = d_in[2];
    const void* Wl0 = d_in[3];
    const void* bl0 = d_in[4];
    const void* Wr0 = d_in[5];
    const void* g0 = d_in[6];
    const void* be0 = d_in[7];
    const void* Wl1 = d_in[8];
    const void* bl1 = d_in[9];
    const void* Wr1 = d_in[10];
    const void* g1 = d_in[11];
    const void* be1 = d_in[12];
    const void* Wl2 = d_in[13];
    const void* bl2 = d_in[14];
    const void* Wr2 = d_in[15];
    const void* g2 = d_in[16];
    const void* be2 = d_in[17];
    const void* cW1 = d_in[18];
    const void* cb1 = d_in[19];
    const void* cW2 = d_in[20];
    const void* cb2 = d_in[21];

    const int N = in_sizes[0] / 128;  // 50000
    const int E = in_sizes[1] / 2;    // 600000
    const int G = 64;

    // workspace carve-up (256B aligned slots)
    char* w = (char*)d_ws;
    size_t o = 0;
    auto take = [&](size_t bytes) -> void* {
        void* p = w + o;
        o = (o + bytes + 255) & ~(size_t)255;
        return p;
    };
    int nb1 = (N + 255) / 256;  // scan phase-1 blocks
    int* flags  = (int*)take(4 * 4);
    int* rowptr = (int*)take((size_t)(N + 1) * 4);
    int* cursor = (int*)take((size_t)N * 4);
    int* deg    = (int*)take((size_t)N * 4);
    int* bsum   = (int*)take((size_t)nb1 * 4);
    int* boff   = (int*)take((size_t)nb1 * 4);
    int* col    = (int*)take((size_t)E * 4);
    int* src32  = (int*)take((size_t)E * 4);
    int* dst32  = (int*)take((size_t)E * 4);
    int* bounds = (int*)take((size_t)(G + 1) * 4);
    float* Z    = (float*)take((size_t)G * 128 * 4);
    ushort_t* Wb0 = (ushort_t*)take((size_t)128 * 256 * 2);
    ushort_t* Wb1 = (ushort_t*)take((size_t)128 * 256 * 2);
    ushort_t* Wb2 = (ushort_t*)take((size_t)64 * 256 * 2);
    ushort_t* AGG = (ushort_t*)take((size_t)N * 128 * 2);
    ushort_t* H1  = (ushort_t*)take((size_t)N * 128 * 2);
    ushort_t* H2  = (ushort_t*)take((size_t)N * 128 * 2);
    ushort_t* XB  = H2;  // x-as-bf16 overlays H2: XB dead before H2 is first written
    ushort_t* H3  = H1;  // [N,64], reuses H1
    if (o > ws_size) return;  // ws too small -> zeros signature (diagnostic)

    int eb = (E + 255) / 256;
    k_detect<<<1, 64, 0, stream>>>(Wl0, ei, flags);
    k_zero<<<nb1, 256, 0, stream>>>(deg, Z, N);
    k_xconv<<<(N * 128 / 4 + 255) / 256, 256, 0, stream>>>(x, flags, XB, N * 128 / 4);
    k_edges<<<eb, 256, 0, stream>>>(ei, E, N, flags, src32, dst32, deg);
    k_scan1<<<nb1, 256, 0, stream>>>(deg, N, rowptr, bsum);
    k_scan2<<<1, 256, 0, stream>>>(bsum, nb1, boff, rowptr + N);
    k_scan3<<<nb1, 256, 0, stream>>>(rowptr, boff, cursor, N);
    k_fill<<<eb, 256, 0, stream>>>(src32, dst32, E, N, cursor, col);
    k_bounds<<<1, 128, 0, stream>>>(batch, N, G, flags, bounds);
    k_wprep<128><<<128, 256, 0, stream>>>(Wl0, Wr0, flags, Wb0);
    k_wprep<128><<<128, 256, 0, stream>>>(Wl1, Wr1, flags, Wb1);
    k_wprep<64><<<64, 256, 0, stream>>>(Wl2, Wr2, flags, Wb2);

    int gb = (N + 255) / 256;  // gemm blocks (4 waves x 64 rows)
    int ab = (N + 3) / 4;      // agg blocks (4 waves = 4 nodes each)

    // layer 0: XB -> H1
    k_agg<<<ab, 256, 0, stream>>>(XB, rowptr, col, AGG, N);
    k_gemm_ln<128><<<gb, 256, 0, stream>>>(AGG, XB, Wb0, bl0, g0, be0, flags, H1, N);
    // layer 1: H1 -> H2 (overwrites XB; XB dead)
    k_agg<<<ab, 256, 0, stream>>>(H1, rowptr, col, AGG, N);
    k_gemm_ln<128><<<gb, 256, 0, stream>>>(AGG, H1, Wb1, bl1, g1, be1, flags, H2, N);
    // layer 2: H2 -> H3 [N,64]
    k_agg<<<ab, 256, 0, stream>>>(H2, rowptr, col, AGG, N);
    k_gemm_ln<64><<<gb, 256, 0, stream>>>(AGG, H2, Wb2, bl2, g2, be2, flags, H3, N);

    k_pool<<<G * 8, 256, 0, stream>>>(H3, bounds, Z, N);
    k_mlp<<<G, 128, 0, stream>>>(Z, bounds, cW1, cb1, cW2, cb2, flags, d_out);
}

// Round 10
// 379.895 us; speedup vs baseline: 2.0178x; 1.0347x over previous
//
#include <hip/hip_runtime.h>

typedef unsigned short ushort_t;
typedef short s16x8 __attribute__((ext_vector_type(8)));
typedef float f32x4 __attribute__((ext_vector_type(4)));

#define LN_EPS 1e-5f

// ---- bf16 <-> f32 helpers ----
__device__ __forceinline__ float b2f(ushort_t u) {
    return __uint_as_float(((unsigned)u) << 16);
}
__device__ __forceinline__ ushort_t f2b(float f) {
    unsigned b = __float_as_uint(f);
    b += 0x7FFFu + ((b >> 16) & 1u);  // round-to-nearest-even
    return (ushort_t)(b >> 16);
}
__device__ __forceinline__ unsigned f2b2(float lo, float hi) {  // pack two bf16
    return (unsigned)f2b(lo) | ((unsigned)f2b(hi) << 16);
}
// dtype-flexible load: isF ? fp32 : bf16
__device__ __forceinline__ float ldf(const void* p, size_t i, int isF) {
    return isF ? ((const float*)p)[i] : b2f(((const ushort_t*)p)[i]);
}

// harness-compat symbol (unused)
__global__ void GraphSAGE_36026185678961_kernel() {}

// ---------------- dtype detect (block 0) + zero-init (all blocks) ----------------
// flags[0]=1 if float inputs fp32; flags[1]=1 if ints int64
__global__ void k_detect_zero(const void* w0, const void* ei, int* __restrict__ flags,
                              int* __restrict__ deg, float* __restrict__ Z, int N) {
    int i = blockIdx.x * blockDim.x + threadIdx.x;
    if (i < N) deg[i] = 0;
    if (i < 64 * 128) Z[i] = 0.f;
    if (blockIdx.x == 0 && threadIdx.x < 64) {
        int t = threadIdx.x;
        const ushort_t* u = (const ushort_t*)w0;
        int pass = 0;
        #pragma unroll
        for (int k = 0; k < 4; ++k) {
            ushort_t v = u[t * 4 + k];
            int ex = (v >> 7) & 0xFF;
            if (ex == 0 || (ex >= 0x60 && ex <= 0x7E)) pass++;
        }
        const unsigned* w = (const unsigned*)ei;
        int nz = (w[2 * t + 1] != 0u) ? 1 : 0;
        #pragma unroll
        for (int off = 32; off; off >>= 1) {
            pass += __shfl_down(pass, off, 64);
            nz += __shfl_down(nz, off, 64);
        }
        if (t == 0) {
            flags[0] = (pass < 205) ? 1 : 0;
            flags[1] = (nz == 0) ? 1 : 0;
        }
    }
}

// ---------------- x -> bf16 conversion (layer-0 input) ----------------
__global__ void k_xconv(const void* X, const int* __restrict__ flags,
                        ushort_t* __restrict__ XB, int total4) {
    int idx = blockIdx.x * blockDim.x + threadIdx.x;
    if (idx >= total4) return;
    if (flags[0]) {
        float4 v = ((const float4*)X)[idx];
        ushort4 o;
        o.x = f2b(v.x); o.y = f2b(v.y); o.z = f2b(v.z); o.w = f2b(v.w);
        ((ushort4*)XB)[idx] = o;
    } else {
        ((ushort4*)XB)[idx] = ((const ushort4*)X)[idx];
    }
}

// ---------------- edge conversion to int32 + degree histogram (fused) ----------------
__global__ void k_edges(const void* ei, int E, int N, const int* __restrict__ flags,
                        int* __restrict__ s32, int* __restrict__ d32, int* __restrict__ deg) {
    int e = blockIdx.x * blockDim.x + threadIdx.x;
    if (e >= E) return;
    int s, d;
    if (flags[1]) {
        const long long* p = (const long long*)ei;
        s = (int)p[e];
        d = (int)p[E + e];
    } else {
        const int* p = (const int*)ei;
        s = p[e];
        d = p[E + e];
    }
    s32[e] = s;
    d32[e] = d;
    if ((unsigned)d < (unsigned)N) atomicAdd(&deg[d], 1);
}

// hierarchical scan, phase 1: per-block (256-elem) exclusive scan + block totals
__global__ void k_scan1(const int* __restrict__ deg, int N,
                        int* __restrict__ rowptr, int* __restrict__ bsum) {
    __shared__ int wsum[4];
    __shared__ int wpre[4];
    int tid = threadIdx.x;
    int lane = tid & 63;
    int w = tid >> 6;
    int i = blockIdx.x * 256 + tid;
    int v = (i < N) ? deg[i] : 0;
    int x = v;
    #pragma unroll
    for (int off = 1; off < 64; off <<= 1) {
        int t = __shfl_up(x, off, 64);
        if (lane >= off) x += t;
    }
    if (lane == 63) wsum[w] = x;
    __syncthreads();
    if (tid == 0) {
        int a = wsum[0]; wpre[0] = a;
        a += wsum[1]; wpre[1] = a;
        a += wsum[2]; wpre[2] = a;
        a += wsum[3]; wpre[3] = a;
    }
    __syncthreads();
    int woff = (w == 0) ? 0 : wpre[w - 1];
    if (i < N) rowptr[i] = woff + x - v;  // block-local exclusive
    if (tid == 0) bsum[blockIdx.x] = wpre[3];
}

// phase 2: single-block exclusive scan of block sums + graph bounds (fused)
__global__ void k_scan2(const int* __restrict__ bsum, int nb,
                        int* __restrict__ boff, int* __restrict__ rowptrN,
                        const void* batch, int N, int G, const int* __restrict__ flags,
                        int* __restrict__ bounds) {
    __shared__ int wsum[4];
    __shared__ int wpre[4];
    int tid = threadIdx.x;
    int lane = tid & 63;
    int w = tid >> 6;
    int run = 0;
    for (int base = 0; base < nb; base += 256) {
        int i = base + tid;
        int v = (i < nb) ? bsum[i] : 0;
        int x = v;
        #pragma unroll
        for (int off = 1; off < 64; off <<= 1) {
            int t = __shfl_up(x, off, 64);
            if (lane >= off) x += t;
        }
        if (lane == 63) wsum[w] = x;
        __syncthreads();
        if (tid == 0) {
            int a = wsum[0]; wpre[0] = a;
            a += wsum[1]; wpre[1] = a;
            a += wsum[2]; wpre[2] = a;
            a += wsum[3]; wpre[3] = a;
        }
        __syncthreads();
        int woff = (w == 0) ? 0 : wpre[w - 1];
        if (i < nb) boff[i] = run + woff + x - v;
        int tot = wpre[3];
        __syncthreads();
        run += tot;
    }
    if (tid == 0) *rowptrN = run;  // rowptr[N] = E_total
    // graph bounds via binary search (threads 0..G)
    if (tid <= G) {
        int isL = flags[1];
        int lo = 0, hi = N;
        while (lo < hi) {
            int mid = (lo + hi) >> 1;
            int bv = isL ? (int)((const long long*)batch)[mid] : ((const int*)batch)[mid];
            if (bv < tid) lo = mid + 1; else hi = mid;
        }
        bounds[tid] = lo;
    }
}

// phase 3: add block offsets; produce cursor copy
__global__ void k_scan3(int* __restrict__ rowptr, const int* __restrict__ boff,
                        int* __restrict__ cursor, int N) {
    int i = blockIdx.x * 256 + threadIdx.x;
    if (i < N) {
        int r = rowptr[i] + boff[i >> 8];
        rowptr[i] = r;
        cursor[i] = r;
    }
}

__global__ void k_fill(const int* __restrict__ src, const int* __restrict__ dst, int E, int N,
                       int* __restrict__ cursor, int* __restrict__ col) {
    int e = blockIdx.x * blockDim.x + threadIdx.x;
    if (e < E) {
        int d = dst[e];
        if ((unsigned)d < (unsigned)N) {
            int p = atomicAdd(&cursor[d], 1);
            if ((unsigned)p < (unsigned)E) {
                int s = src[e];
                col[p] = ((unsigned)s < (unsigned)N) ? s : 0;
            }
        }
    }
}

// ---------------- mean aggregation: AGG[i] = mean_{j in N(i)} X[j]  (bf16, 128-wide) ----------------
// one wave per node; lane-quarter qn (16 lanes) handles neighbor slot qn; each lane loads
// uint4 = 8 bf16 (16B), so one wave instruction gathers 4 neighbor rows. Unroll x2.
__global__ __launch_bounds__(256) void k_agg(
    const ushort_t* __restrict__ X, const int* __restrict__ rowptr,
    const int* __restrict__ col, ushort_t* __restrict__ AGG, int N) {
    int i = blockIdx.x * 4 + (threadIdx.x >> 6);
    if (i >= N) return;
    int l = threadIdx.x & 63;
    int qn = l >> 4;   // neighbor slot 0..3
    int fo = l & 15;   // feature octet: feats 8*fo .. 8*fo+7
    const uint4* X8 = (const uint4*)X;  // row = 16 uint4 groups
    int s = rowptr[i], e = rowptr[i + 1];
    float al[4] = {0.f, 0.f, 0.f, 0.f};  // low bf16 of words x,y,z,w
    float ah[4] = {0.f, 0.f, 0.f, 0.f};  // high bf16
    int p = s + qn;
    for (; p + 4 < e; p += 8) {  // 8 neighbors per wave-iter, 2 loads/lane in flight
        int j0 = col[p], j1 = col[p + 4];
        uint4 u0 = X8[(size_t)j0 * 16 + fo];
        uint4 u1 = X8[(size_t)j1 * 16 + fo];
        unsigned w0[4] = {u0.x, u0.y, u0.z, u0.w};
        unsigned w1[4] = {u1.x, u1.y, u1.z, u1.w};
        #pragma unroll
        for (int k = 0; k < 4; ++k) {
            al[k] += __uint_as_float(w0[k] << 16) + __uint_as_float(w1[k] << 16);
            ah[k] += __uint_as_float(w0[k] & 0xFFFF0000u) + __uint_as_float(w1[k] & 0xFFFF0000u);
        }
    }
    for (; p < e; p += 4) {
        int j = col[p];
        uint4 u = X8[(size_t)j * 16 + fo];
        unsigned w0[4] = {u.x, u.y, u.z, u.w};
        #pragma unroll
        for (int k = 0; k < 4; ++k) {
            al[k] += __uint_as_float(w0[k] << 16);
            ah[k] += __uint_as_float(w0[k] & 0xFFFF0000u);
        }
    }
    // reduce across the 4 neighbor slots (lanes 16 apart)
    #pragma unroll
    for (int k = 0; k < 4; ++k) {
        al[k] += __shfl_xor(al[k], 16, 64);
        al[k] += __shfl_xor(al[k], 32, 64);
        ah[k] += __shfl_xor(ah[k], 16, 64);
        ah[k] += __shfl_xor(ah[k], 32, 64);
    }
    if (qn == 0) {
        int d = e - s;
        float inv = 1.f / (float)(d > 0 ? d : 1);
        uint4 o;
        o.x = f2b2(al[0] * inv, ah[0] * inv);
        o.y = f2b2(al[1] * inv, ah[1] * inv);
        o.z = f2b2(al[2] * inv, ah[2] * inv);
        o.w = f2b2(al[3] * inv, ah[3] * inv);
        ((uint4*)AGG)[(size_t)i * 16 + fo] = o;
    }
}

// ---------------- weight prep (all 3 layers fused): Wb[f][k] bf16 ----------------
__global__ void k_wprep(const void* Wl0, const void* Wr0, const void* Wl1, const void* Wr1,
                        const void* Wl2, const void* Wr2, const int* __restrict__ flags,
                        ushort_t* __restrict__ Wb0, ushort_t* __restrict__ Wb1,
                        ushort_t* __restrict__ Wb2) {
    int t = blockIdx.x * blockDim.x + threadIdx.x;
    int isF = flags[0];
    const void* Wl;
    const void* Wr;
    ushort_t* Wb;
    int base;
    if (t < 256 * 128) { Wl = Wl0; Wr = Wr0; Wb = Wb0; base = t; }
    else if (t < 2 * 256 * 128) { Wl = Wl1; Wr = Wr1; Wb = Wb1; base = t - 256 * 128; }
    else if (t < 2 * 256 * 128 + 256 * 64) { Wl = Wl2; Wr = Wr2; Wb = Wb2; base = t - 2 * 256 * 128; }
    else return;
    int f = base >> 8, k = base & 255;
    float v = (k < 128) ? ldf(Wl, f * 128 + k, isF) : ldf(Wr, f * 128 + (k - 128), isF);
    Wb[base] = isF ? f2b(v) : ((const ushort_t*)((k < 128) ? Wl : Wr))[f * 128 + (k & 127)];
}

// ---------------- fused MFMA GEMM + bias + LayerNorm + ReLU ----------------
// One wave: R=4 row-tiles (64 rows) x FO cols; B-frag loaded once per (kk,nt), reused x4.
template <int FO>
__global__ __launch_bounds__(256, 2) void k_gemm_ln(
    const ushort_t* __restrict__ AGG, const ushort_t* __restrict__ X,
    const ushort_t* __restrict__ Wb,  // [FO][256] bf16
    const void* bl, const void* gam, const void* bet,
    const int* __restrict__ flags,
    ushort_t* __restrict__ H, int M) {
    constexpr int NT = FO / 16;
    constexpr int R = 4;
    int lane = threadIdx.x & 63;
    int wid = threadIdx.x >> 6;
    int wrow0 = (blockIdx.x * 4 + wid) * (R * 16);
    if (wrow0 >= M) return;
    int isF = flags[0];
    int m = lane & 15;
    int q = lane >> 4;

    int arow[R];
    #pragma unroll
    for (int r = 0; r < R; ++r) {
        int ar = wrow0 + r * 16 + m;
        arow[r] = (ar < M) ? ar : (M - 1);  // tail clamp; stores guarded below
    }

    f32x4 acc[R][NT];
    #pragma unroll
    for (int r = 0; r < R; ++r)
        #pragma unroll
        for (int nt = 0; nt < NT; ++nt) acc[r][nt] = (f32x4){0.f, 0.f, 0.f, 0.f};

    #pragma unroll
    for (int kk = 0; kk < 8; ++kk) {
        const ushort_t* base = (kk < 4) ? AGG : X;
        int ko = (kk & 3) * 32 + q * 8;
        s16x8 a[R];
        #pragma unroll
        for (int r = 0; r < R; ++r)
            a[r] = *(const s16x8*)(base + (size_t)arow[r] * 128 + ko);
        #pragma unroll
        for (int nt = 0; nt < NT; ++nt) {
            s16x8 b = *(const s16x8*)(Wb + (size_t)(nt * 16 + m) * 256 + kk * 32 + q * 8);
            #pragma unroll
            for (int r = 0; r < R; ++r)
                acc[r][nt] = __builtin_amdgcn_mfma_f32_16x16x32_bf16(a[r], b, acc[r][nt], 0, 0, 0);
        }
    }

    // epilogue per row-tile: bias + LN + ReLU + store
    #pragma unroll
    for (int r = 0; r < R; ++r) {
        #pragma unroll
        for (int nt = 0; nt < NT; ++nt) {
            float bv = ldf(bl, nt * 16 + m, isF);
            #pragma unroll
            for (int rr = 0; rr < 4; ++rr) acc[r][nt][rr] += bv;
        }
        float mu[4], rs[4];
        #pragma unroll
        for (int rr = 0; rr < 4; ++rr) {
            float s1 = 0.f, s2 = 0.f;
            #pragma unroll
            for (int nt = 0; nt < NT; ++nt) {
                float v = acc[r][nt][rr];
                s1 += v;
                s2 += v * v;
            }
            #pragma unroll
            for (int off = 1; off < 16; off <<= 1) {
                s1 += __shfl_xor(s1, off, 64);
                s2 += __shfl_xor(s2, off, 64);
            }
            float mm = s1 / (float)FO;
            float var = s2 / (float)FO - mm * mm;
            var = var > 0.f ? var : 0.f;
            mu[rr] = mm;
            rs[rr] = rsqrtf(var + LN_EPS);
        }
        #pragma unroll
        for (int nt = 0; nt < NT; ++nt) {
            int n0 = nt * 16 + m;
            float g = ldf(gam, n0, isF);
            float be = ldf(bet, n0, isF);
            #pragma unroll
            for (int rr = 0; rr < 4; ++rr) {
                int row = wrow0 + r * 16 + q * 4 + rr;
                if (row < M) {
                    float y = (acc[r][nt][rr] - mu[rr]) * rs[rr] * g + be;
                    y = y > 0.f ? y : 0.f;
                    H[(size_t)row * FO + n0] = f2b(y);
                }
            }
        }
    }
}

// ---------------- pooling: Z[64][128]: cols 0..63 sum, 64..127 max ----------------
__global__ void k_pool(const ushort_t* __restrict__ H,  // [N,64], post-ReLU (>=0)
                       const int* __restrict__ bounds, float* __restrict__ Z, int N) {
    int g = blockIdx.x >> 3;
    int chunk = blockIdx.x & 7;
    int f = threadIdx.x & 63;
    int sub = threadIdx.x >> 6;
    int strm = chunk * 4 + sub;
    int s = bounds[g], e = bounds[g + 1];
    s = s < 0 ? 0 : (s > N ? N : s);
    e = e < s ? s : (e > N ? N : e);
    float sum = 0.f, mx = 0.f;
    for (int i = s + strm; i < e; i += 32) {
        float v = b2f(H[(size_t)i * 64 + f]);
        sum += v;
        mx = mx > v ? mx : v;
    }
    atomicAdd(&Z[g * 128 + f], sum);
    atomicMax((int*)&Z[g * 128 + 64 + f], __float_as_int(mx));
}

// ---------------- final MLP; output dtype follows flags[0] ----------------
__global__ void k_mlp(const float* __restrict__ Z, const int* __restrict__ bounds,
                      const void* cW1, const void* cb1, const void* cW2, const void* cb2,
                      const int* __restrict__ flags, void* __restrict__ out) {
    int g = blockIdx.x;
    int f = threadIdx.x;  // 0..127
    int isF = flags[0];
    __shared__ float z[128];
    __shared__ float hid[128];
    __shared__ float r0[2], r1[2];
    int cnt = bounds[g + 1] - bounds[g];
    float c = (float)(cnt > 0 ? cnt : 1);
    float zv = Z[g * 128 + f];
    if (f < 64) zv /= c;
    z[f] = zv;
    __syncthreads();
    float acc = ldf(cb1, f, isF);
    #pragma unroll 8
    for (int k = 0; k < 128; ++k) acc += z[k] * ldf(cW1, f * 128 + k, isF);
    acc = acc > 0.f ? acc : 0.f;
    hid[f] = acc;
    __syncthreads();
    float p0 = hid[f] * ldf(cW2, f, isF);
    float p1 = hid[f] * ldf(cW2, 128 + f, isF);
    #pragma unroll
    for (int off = 32; off > 0; off >>= 1) {
        p0 += __shfl_xor(p0, off, 64);
        p1 += __shfl_xor(p1, off, 64);
    }
    int w = f >> 6;
    if ((f & 63) == 0) { r0[w] = p0; r1[w] = p1; }
    __syncthreads();
    if (f == 0) {
        float v0 = r0[0] + r0[1] + ldf(cb2, 0, isF);
        float v1 = r1[0] + r1[1] + ldf(cb2, 1, isF);
        if (isF) {
            ((float*)out)[g * 2 + 0] = v0;
            ((float*)out)[g * 2 + 1] = v1;
        } else {
            ((ushort_t*)out)[g * 2 + 0] = f2b(v0);
            ((ushort_t*)out)[g * 2 + 1] = f2b(v1);
        }
    }
}

// ---------------- launch ----------------
extern "C" void kernel_launch(void* const* d_in, const int* in_sizes, int n_in,
                              void* d_out, int out_size, void* d_ws, size_t ws_size,
                              hipStream_t stream) {
    const void* x = d_in[0];
    const void* ei = d_in[1];
    const void* batch = d_in[2];
    const void* Wl0 = d_in[3];
    const void* bl0 = d_in[4];
    const void* Wr0 = d_in[5];
    const void* g0 = d_in[6];
    const void* be0 = d_in[7];
    const void* Wl1 = d_in[8];
    const void* bl1 = d_in[9];
    const void* Wr1 = d_in[10];
    const void* g1 = d_in[11];
    const void* be1 = d_in[12];
    const void* Wl2 = d_in[13];
    const void* bl2 = d_in[14];
    const void* Wr2 = d_in[15];
    const void* g2 = d_in[16];
    const void* be2 = d_in[17];
    const void* cW1 = d_in[18];
    const void* cb1 = d_in[19];
    const void* cW2 = d_in[20];
    const void* cb2 = d_in[21];

    const int N = in_sizes[0] / 128;  // 50000
    const int E = in_sizes[1] / 2;    // 600000
    const int G = 64;

    // workspace carve-up (256B aligned slots)
    char* w = (char*)d_ws;
    size_t o = 0;
    auto take = [&](size_t bytes) -> void* {
        void* p = w + o;
        o = (o + bytes + 255) & ~(size_t)255;
        return p;
    };
    int nb1 = (N + 255) / 256;  // scan phase-1 blocks
    int* flags  = (int*)take(4 * 4);
    int* rowptr = (int*)take((size_t)(N + 1) * 4);
    int* cursor = (int*)take((size_t)N * 4);
    int* deg    = (int*)take((size_t)N * 4);
    int* bsum   = (int*)take((size_t)nb1 * 4);
    int* boff   = (int*)take((size_t)nb1 * 4);
    int* col    = (int*)take((size_t)E * 4);
    int* src32  = (int*)take((size_t)E * 4);
    int* dst32  = (int*)take((size_t)E * 4);
    int* bounds = (int*)take((size_t)(G + 1) * 4);
    float* Z    = (float*)take((size_t)G * 128 * 4);
    ushort_t* Wb0 = (ushort_t*)take((size_t)128 * 256 * 2);
    ushort_t* Wb1 = (ushort_t*)take((size_t)128 * 256 * 2);
    ushort_t* Wb2 = (ushort_t*)take((size_t)64 * 256 * 2);
    ushort_t* AGG = (ushort_t*)take((size_t)N * 128 * 2);
    ushort_t* H1  = (ushort_t*)take((size_t)N * 128 * 2);
    ushort_t* H2  = (ushort_t*)take((size_t)N * 128 * 2);
    ushort_t* XB  = H2;  // x-as-bf16 overlays H2: XB dead before H2 is first written
    ushort_t* H3  = H1;  // [N,64], reuses H1
    if (o > ws_size) return;  // ws too small -> zeros signature (diagnostic)

    int eb = (E + 255) / 256;
    k_detect_zero<<<nb1, 256, 0, stream>>>(Wl0, ei, flags, deg, Z, N);
    k_xconv<<<(N * 128 / 4 + 255) / 256, 256, 0, stream>>>(x, flags, XB, N * 128 / 4);
    k_edges<<<eb, 256, 0, stream>>>(ei, E, N, flags, src32, dst32, deg);
    k_scan1<<<nb1, 256, 0, stream>>>(deg, N, rowptr, bsum);
    k_scan2<<<1, 256, 0, stream>>>(bsum, nb1, boff, rowptr + N, batch, N, G, flags, bounds);
    k_scan3<<<nb1, 256, 0, stream>>>(rowptr, boff, cursor, N);
    k_fill<<<eb, 256, 0, stream>>>(src32, dst32, E, N, cursor, col);
    k_wprep<<<(2 * 256 * 128 + 256 * 64 + 255) / 256, 256, 0, stream>>>(
        Wl0, Wr0, Wl1, Wr1, Wl2, Wr2, flags, Wb0, Wb1, Wb2);

    int gb = (N + 255) / 256;  // gemm blocks (4 waves x 64 rows)
    int ab = (N + 3) / 4;      // agg blocks (4 waves = 4 nodes each)

    // layer 0: XB -> H1
    k_agg<<<ab, 256, 0, stream>>>(XB, rowptr, col, AGG, N);
    k_gemm_ln<128><<<gb, 256, 0, stream>>>(AGG, XB, Wb0, bl0, g0, be0, flags, H1, N);
    // layer 1: H1 -> H2 (overwrites XB; XB dead)
    k_agg<<<ab, 256, 0, stream>>>(H1, rowptr, col, AGG, N);
    k_gemm_ln<128><<<gb, 256, 0, stream>>>(AGG, H1, Wb1, bl1, g1, be1, flags, H2, N);
    // layer 2: H2 -> H3 [N,64]
    k_agg<<<ab, 256, 0, stream>>>(H2, rowptr, col, AGG, N);
    k_gemm_ln<64><<<gb, 256, 0, stream>>>(AGG, H2, Wb2, bl2, g2, be2, flags, H3, N);

    k_pool<<<G * 8, 256, 0, stream>>>(H3, bounds, Z, N);
    k_mlp<<<G, 128, 0, stream>>>(Z, bounds, cW1, cb1, cW2, cb2, flags, d_out);
}